// Round 7
// baseline (20252.954 us; speedup 1.0000x reference)
//
#include <hip/hip_runtime.h>

#define NAGENTS 32
#define NOBSV   2
#define H1D     128
#define HXD     64
#define NACTD   5
#define TBATCH  8
#define NTHREADS 256
#define NWAVES  4
#define BFST    2056    // _Float16 elems per batch row of s_hid (32*64 + 8 pad)
#define HROWST  132     // s_h row stride in floats (128 + 4 pad -> bank spread)
#define PFD     8       // prefetch pipeline depth (k-steps in flight)

typedef _Float16 half8 __attribute__((ext_vector_type(8)));

// 256 threads = 4 waves. Wave w owns agents 8w..8w+7.
// lane = og*8 + lb: og in 0..7 (8-out slice / 16-wide h slice), lb in 0..7 (batch).
// LDS: s_obs 2.1 KB + s_hid(f16) 32.9 KB + s_h 16.9 KB = 50.7 KB -> 3 blocks/CU.
// Hot loops use an 8-deep rotating register prefetch pipeline (static k&7
// indexing, fully unrolled) to cover ~250-cycle L2 latency on weight streams.
__global__ __launch_bounds__(NTHREADS, 3) void qnet_fused(
    const float* __restrict__ obs,
    const float* __restrict__ W1, const float* __restrict__ b1,
    const float* __restrict__ W2, const float* __restrict__ b2,
    const float* __restrict__ Wc, const float* __restrict__ bc,
    const float* __restrict__ Wd, const float* __restrict__ bd,
    float* __restrict__ out)
{
    __shared__ float    s_obs[TBATCH][NAGENTS * 2 + 2];
    __shared__ _Float16 s_hid[TBATCH * BFST];
    __shared__ float    s_h[NWAVES][TBATCH][HROWST];

    const int tid  = threadIdx.x;
    const int wave = tid >> 6;
    const int lane = tid & 63;
    const int lb   = lane & 7;
    const int og   = lane >> 3;
    const int b0   = blockIdx.x * TBATCH;

    // ---- load obs tile ----
    {
        const float2* src = reinterpret_cast<const float2*>(obs + (size_t)b0 * (NAGENTS * NOBSV));
        float2 v = src[tid];
        s_obs[tid >> 5][(tid & 31) * 2 + 0] = v.x;
        s_obs[tid >> 5][(tid & 31) * 2 + 1] = v.y;
    }
    __syncthreads();

    // ---- phase 1: neighbor mask in f64 (bit-matches numpy-f64 reference) ----
    const int p_a = tid >> 3;
    const int p_b = tid & 7;
    unsigned int bits = 0u;
    float Jf;
    {
        const double xi = (double)s_obs[p_b][p_a * 2 + 0] * 2.0;
        const double yi = (double)s_obs[p_b][p_a * 2 + 1] * 6.0;
        #pragma unroll
        for (int j = 0; j < NAGENTS; ++j) {
            double xj = (double)s_obs[p_b][j * 2 + 0] * 2.0;
            double yj = (double)s_obs[p_b][j * 2 + 1] * 6.0;
            double d = fabs(xi - xj) + fabs(yi - yj);
            if (d > 0.0 && d < 2.0) bits |= (1u << j);
        }
        Jf = fmaxf((float)__popc(bits), 1.0f);
    }

    // ---- phase 2: encoder. Cooperative h (16/lane, staged f32 in s_h),
    //      then W2 GEMM with 8-deep prefetch pipeline, pack f16 to s_hid. ----
    #pragma unroll 1
    for (int ai = 0; ai < 8; ++ai) {
        const int a = wave * 8 + ai;
        const float o0 = s_obs[lb][a * 2 + 0];
        const float o1 = s_obs[lb][a * 2 + 1];
        {
            const float* __restrict__ w1a = W1 + a * (NOBSV * H1D) + og * 16;
            const float* __restrict__ w1b = w1a + H1D;
            const float* __restrict__ b1p = b1 + a * H1D + og * 16;
            float* hdst = &s_h[wave][lb][og * 16];
            #pragma unroll
            for (int c = 0; c < 4; ++c) {
                float4 wa = *reinterpret_cast<const float4*>(w1a + 4 * c);
                float4 wb = *reinterpret_cast<const float4*>(w1b + 4 * c);
                float4 bv = *reinterpret_cast<const float4*>(b1p + 4 * c);
                float4 hv;
                hv.x = fmaxf(fmaf(o1, wb.x, fmaf(o0, wa.x, bv.x)), 0.0f);
                hv.y = fmaxf(fmaf(o1, wb.y, fmaf(o0, wa.y, bv.y)), 0.0f);
                hv.z = fmaxf(fmaf(o1, wb.z, fmaf(o0, wa.z, bv.z)), 0.0f);
                hv.w = fmaxf(fmaf(o1, wb.w, fmaf(o0, wa.w, bv.w)), 0.0f);
                *reinterpret_cast<float4*>(hdst + 4 * c) = hv;
            }
        }
        asm volatile("s_waitcnt lgkmcnt(0)" ::: "memory");
        __builtin_amdgcn_sched_barrier(0);

        const float* __restrict__ w2p = W2 + a * (H1D * HXD) + og * 8;
        const float* __restrict__ b2p = b2 + a * HXD + og * 8;
        float acc[8];
        {
            float4 bv0 = *reinterpret_cast<const float4*>(b2p + 0);
            float4 bv1 = *reinterpret_cast<const float4*>(b2p + 4);
            acc[0] = bv0.x; acc[1] = bv0.y; acc[2] = bv0.z; acc[3] = bv0.w;
            acc[4] = bv1.x; acc[5] = bv1.y; acc[6] = bv1.z; acc[7] = bv1.w;
        }
        const float* hsrc = &s_h[wave][lb][0];
        float4 pw0[PFD], pw1[PFD];
        #pragma unroll
        for (int i = 0; i < PFD; ++i) {
            pw0[i] = *reinterpret_cast<const float4*>(w2p + i * HXD);
            pw1[i] = *reinterpret_cast<const float4*>(w2p + i * HXD + 4);
        }
        #pragma unroll
        for (int k = 0; k < H1D; ++k) {
            const int s = k & (PFD - 1);
            float4 wv0 = pw0[s];
            float4 wv1 = pw1[s];
            if (k + PFD < H1D) {
                pw0[s] = *reinterpret_cast<const float4*>(w2p + (k + PFD) * HXD);
                pw1[s] = *reinterpret_cast<const float4*>(w2p + (k + PFD) * HXD + 4);
            }
            const float hv = hsrc[k];
            acc[0] = fmaf(hv, wv0.x, acc[0]);
            acc[1] = fmaf(hv, wv0.y, acc[1]);
            acc[2] = fmaf(hv, wv0.z, acc[2]);
            acc[3] = fmaf(hv, wv0.w, acc[3]);
            acc[4] = fmaf(hv, wv1.x, acc[4]);
            acc[5] = fmaf(hv, wv1.y, acc[5]);
            acc[6] = fmaf(hv, wv1.z, acc[6]);
            acc[7] = fmaf(hv, wv1.w, acc[7]);
        }
        half8 hh;
        #pragma unroll
        for (int i = 0; i < 8; ++i) hh[i] = (_Float16)fmaxf(acc[i], 0.0f);
        *reinterpret_cast<half8*>(&s_hid[lb * BFST + a * HXD + og * 8]) = hh;
    }
    __syncthreads();

    // ---- phase 3+4 fused per agent ----
    #pragma unroll 1
    for (int ai = 0; ai < 8; ++ai) {
        const int a = wave * 8 + ai;
        const int srcm = ai * 8 + lb;
        const unsigned int mbits = (unsigned int)__shfl((int)bits, srcm, 64);
        const float Jv = __shfl(Jf, srcm, 64);

        // comms slice: branchless masked sum over neighbor rows (m in {0,1})
        float cm8[8];
        #pragma unroll
        for (int i = 0; i < 8; ++i) cm8[i] = 0.0f;
        {
            const _Float16* hrow = &s_hid[lb * BFST + og * 8];
            #pragma unroll 8
            for (int j = 0; j < NAGENTS; ++j) {
                const float m = (float)((mbits >> j) & 1u);
                half8 v = *reinterpret_cast<const half8*>(hrow + j * HXD);
                cm8[0] = fmaf(m, (float)v[0], cm8[0]);
                cm8[1] = fmaf(m, (float)v[1], cm8[1]);
                cm8[2] = fmaf(m, (float)v[2], cm8[2]);
                cm8[3] = fmaf(m, (float)v[3], cm8[3]);
                cm8[4] = fmaf(m, (float)v[4], cm8[4]);
                cm8[5] = fmaf(m, (float)v[5], cm8[5]);
                cm8[6] = fmaf(m, (float)v[6], cm8[6]);
                cm8[7] = fmaf(m, (float)v[7], cm8[7]);
            }
        }
        {
            float* cw = &s_h[wave][lb][og * 8];
            *reinterpret_cast<float4*>(cw + 0) =
                make_float4(cm8[0]/Jv, cm8[1]/Jv, cm8[2]/Jv, cm8[3]/Jv);
            *reinterpret_cast<float4*>(cw + 4) =
                make_float4(cm8[4]/Jv, cm8[5]/Jv, cm8[6]/Jv, cm8[7]/Jv);
        }
        asm volatile("s_waitcnt lgkmcnt(0)" ::: "memory");
        __builtin_amdgcn_sched_barrier(0);

        const float* __restrict__ wcp = Wc + a * (2 * HXD * HXD) + og * 8;
        const float* __restrict__ bcp = bc + a * HXD + og * 8;
        float acc[8];
        {
            float4 bv0 = *reinterpret_cast<const float4*>(bcp + 0);
            float4 bv1 = *reinterpret_cast<const float4*>(bcp + 4);
            acc[0] = bv0.x; acc[1] = bv0.y; acc[2] = bv0.z; acc[3] = bv0.w;
            acc[4] = bv1.x; acc[5] = bv1.y; acc[6] = bv1.z; acc[7] = bv1.w;
        }
        const _Float16* hbase = &s_hid[lb * BFST + a * HXD];
        // half 1: k = 0..63, ci = hidden (f16 LDS), pipelined weight stream
        {
            float4 pw0[PFD], pw1[PFD];
            #pragma unroll
            for (int i = 0; i < PFD; ++i) {
                pw0[i] = *reinterpret_cast<const float4*>(wcp + i * HXD);
                pw1[i] = *reinterpret_cast<const float4*>(wcp + i * HXD + 4);
            }
            #pragma unroll
            for (int k = 0; k < HXD; ++k) {
                const int s = k & (PFD - 1);
                float4 wv0 = pw0[s];
                float4 wv1 = pw1[s];
                if (k + PFD < HXD) {
                    pw0[s] = *reinterpret_cast<const float4*>(wcp + (k + PFD) * HXD);
                    pw1[s] = *reinterpret_cast<const float4*>(wcp + (k + PFD) * HXD + 4);
                }
                const float ci = (float)hbase[k];
                acc[0] = fmaf(ci, wv0.x, acc[0]);
                acc[1] = fmaf(ci, wv0.y, acc[1]);
                acc[2] = fmaf(ci, wv0.z, acc[2]);
                acc[3] = fmaf(ci, wv0.w, acc[3]);
                acc[4] = fmaf(ci, wv1.x, acc[4]);
                acc[5] = fmaf(ci, wv1.y, acc[5]);
                acc[6] = fmaf(ci, wv1.z, acc[6]);
                acc[7] = fmaf(ci, wv1.w, acc[7]);
            }
        }
        // half 2: k = 64..127, ci = comms (f32 wave-private staging)
        {
            const float* __restrict__ wc2 = wcp + HXD * HXD;
            float4 pw0[PFD], pw1[PFD];
            #pragma unroll
            for (int i = 0; i < PFD; ++i) {
                pw0[i] = *reinterpret_cast<const float4*>(wc2 + i * HXD);
                pw1[i] = *reinterpret_cast<const float4*>(wc2 + i * HXD + 4);
            }
            #pragma unroll
            for (int k2 = 0; k2 < HXD; ++k2) {
                const int s = k2 & (PFD - 1);
                float4 wv0 = pw0[s];
                float4 wv1 = pw1[s];
                if (k2 + PFD < HXD) {
                    pw0[s] = *reinterpret_cast<const float4*>(wc2 + (k2 + PFD) * HXD);
                    pw1[s] = *reinterpret_cast<const float4*>(wc2 + (k2 + PFD) * HXD + 4);
                }
                const float ci = s_h[wave][lb][k2];
                acc[0] = fmaf(ci, wv0.x, acc[0]);
                acc[1] = fmaf(ci, wv0.y, acc[1]);
                acc[2] = fmaf(ci, wv0.z, acc[2]);
                acc[3] = fmaf(ci, wv0.w, acc[3]);
                acc[4] = fmaf(ci, wv1.x, acc[4]);
                acc[5] = fmaf(ci, wv1.y, acc[5]);
                acc[6] = fmaf(ci, wv1.z, acc[6]);
                acc[7] = fmaf(ci, wv1.w, acc[7]);
            }
        }
        // tanh + decoder partial
        float qv[NACTD];
        #pragma unroll
        for (int o = 0; o < NACTD; ++o) qv[o] = 0.0f;
        const float* __restrict__ wdp = Wd + a * (HXD * NACTD) + og * 8 * NACTD;
        #pragma unroll
        for (int i = 0; i < 8; ++i) {
            float h2 = tanhf(acc[i]);
            #pragma unroll
            for (int o = 0; o < NACTD; ++o)
                qv[o] = fmaf(h2, wdp[i * NACTD + o], qv[o]);
        }
        #pragma unroll
        for (int o = 0; o < NACTD; ++o) {
            qv[o] += __shfl_xor(qv[o], 8, 64);
            qv[o] += __shfl_xor(qv[o], 16, 64);
            qv[o] += __shfl_xor(qv[o], 32, 64);
        }
        if (og == 0) {
            float* op = out + ((size_t)(b0 + lb) * NAGENTS + a) * NACTD;
            const float* bdp = bd + a * NACTD;
            #pragma unroll
            for (int o = 0; o < NACTD; ++o) op[o] = qv[o] + bdp[o];
        }
    }
}

extern "C" void kernel_launch(void* const* d_in, const int* in_sizes, int n_in,
                              void* d_out, int out_size, void* d_ws, size_t ws_size,
                              hipStream_t stream) {
    (void)d_ws; (void)ws_size; (void)out_size;
    if (n_in < 9) return;
    const float* obs = (const float*)d_in[0];
    const float* W1  = (const float*)d_in[1];
    const float* b1v = (const float*)d_in[2];
    const float* W2  = (const float*)d_in[3];
    const float* b2v = (const float*)d_in[4];
    const float* Wc  = (const float*)d_in[5];
    const float* bcv = (const float*)d_in[6];
    const float* Wd  = (const float*)d_in[7];
    const float* bdv = (const float*)d_in[8];
    float* out = (float*)d_out;
    const int Btot = in_sizes[0] / (NAGENTS * NOBSV);  // 16384
    dim3 grid(Btot / TBATCH), block(NTHREADS);
    qnet_fused<<<grid, block, 0, stream>>>(obs, W1, b1v, W2, b2v, Wc, bcv, Wd, bdv, out);
}

// Round 8
// 328.876 us; speedup vs baseline: 61.5824x; 61.5824x over previous
//
#include <hip/hip_runtime.h>

#define NAGENTS 32
#define NOBSV   2
#define H1D     128
#define HXD     64
#define NACTD   5

typedef _Float16 half8 __attribute__((ext_vector_type(8)));

// ============================ Kernel 1: encoder ============================
// grid (B/128, 32). Block: agent a, 128 batch rows. Weights LDS-resident.
// lane = lb*8+og; rows = wave*32 + lb*4 + rr; outputs og*8..+8.
__global__ __launch_bounds__(256, 4) void k1_encoder(
    const float* __restrict__ obs, const float* __restrict__ W1,
    const float* __restrict__ b1, const float* __restrict__ W2,
    const float* __restrict__ b2, _Float16* __restrict__ hid)
{
    __shared__ float s_w1a[H1D], s_w1b[H1D], s_b1[H1D];
    __shared__ float s_w2[H1D][HXD];
    __shared__ float s_b2[HXD];
    __shared__ float s_ob[128][2];

    const int a  = blockIdx.y;
    const int r0 = blockIdx.x * 128;
    const int tid = threadIdx.x;

    {
        const float* w1p = W1 + a * (NOBSV * H1D);
        if (tid < H1D) {
            s_w1a[tid] = w1p[tid];
            s_w1b[tid] = w1p[H1D + tid];
            s_b1[tid]  = b1[a * H1D + tid];
        } else if (tid < H1D + HXD) {
            s_b2[tid - H1D] = b2[a * HXD + (tid - H1D)];
        }
        const float4* w2s = reinterpret_cast<const float4*>(W2 + (size_t)a * (H1D * HXD));
        float4* w2d = reinterpret_cast<float4*>(&s_w2[0][0]);
        #pragma unroll
        for (int c = 0; c < 8; ++c) w2d[tid + c * 256] = w2s[tid + c * 256];
        if (tid < 128) {
            const float2 ov = *reinterpret_cast<const float2*>(
                obs + ((size_t)(r0 + tid) * NAGENTS + a) * NOBSV);
            s_ob[tid][0] = ov.x; s_ob[tid][1] = ov.y;
        }
    }
    __syncthreads();

    const int wv = tid >> 6, lane = tid & 63;
    const int og = lane & 7, lb = lane >> 3;
    const int rbase = wv * 32 + lb * 4;

    float o0[4], o1[4];
    #pragma unroll
    for (int rr = 0; rr < 4; ++rr) { o0[rr] = s_ob[rbase + rr][0]; o1[rr] = s_ob[rbase + rr][1]; }

    float acc[4][8];
    #pragma unroll
    for (int rr = 0; rr < 4; ++rr)
        #pragma unroll
        for (int i = 0; i < 8; ++i) acc[rr][i] = s_b2[og * 8 + i];

    #pragma unroll 4
    for (int k = 0; k < H1D; ++k) {
        const float wa = s_w1a[k], wb = s_w1b[k], bb = s_b1[k];
        float h[4];
        #pragma unroll
        for (int rr = 0; rr < 4; ++rr)
            h[rr] = fmaxf(fmaf(o1[rr], wb, fmaf(o0[rr], wa, bb)), 0.0f);
        const float4 wv0 = *reinterpret_cast<const float4*>(&s_w2[k][og * 8]);
        const float4 wv1 = *reinterpret_cast<const float4*>(&s_w2[k][og * 8 + 4]);
        #pragma unroll
        for (int rr = 0; rr < 4; ++rr) {
            acc[rr][0] = fmaf(h[rr], wv0.x, acc[rr][0]);
            acc[rr][1] = fmaf(h[rr], wv0.y, acc[rr][1]);
            acc[rr][2] = fmaf(h[rr], wv0.z, acc[rr][2]);
            acc[rr][3] = fmaf(h[rr], wv0.w, acc[rr][3]);
            acc[rr][4] = fmaf(h[rr], wv1.x, acc[rr][4]);
            acc[rr][5] = fmaf(h[rr], wv1.y, acc[rr][5]);
            acc[rr][6] = fmaf(h[rr], wv1.z, acc[rr][6]);
            acc[rr][7] = fmaf(h[rr], wv1.w, acc[rr][7]);
        }
    }
    #pragma unroll
    for (int rr = 0; rr < 4; ++rr) {
        half8 hh;
        #pragma unroll
        for (int i = 0; i < 8; ++i) hh[i] = (_Float16)fmaxf(acc[rr][i], 0.0f);
        *reinterpret_cast<half8*>(
            hid + ((size_t)(r0 + rbase + rr) * NAGENTS + a) * HXD + og * 8) = hh;
    }
}

// ========================= Kernel 2: mask + comms =========================
// grid (B/16). Block: 16 batch rows, all agents. Hidden tile in LDS (f16).
__global__ __launch_bounds__(256, 2) void k2_comms(
    const float* __restrict__ obs, const _Float16* __restrict__ hid,
    _Float16* __restrict__ cms)
{
    __shared__ _Float16 s_t[16][NAGENTS * HXD];   // 64 KB
    __shared__ float    s_o[16][NAGENTS * 2];     // 4 KB

    const int r0 = blockIdx.x * 16;
    const int tid = threadIdx.x;
    {
        const half8* src = reinterpret_cast<const half8*>(hid + (size_t)r0 * NAGENTS * HXD);
        half8* dst = reinterpret_cast<half8*>(&s_t[0][0]);
        #pragma unroll
        for (int c = 0; c < 16; ++c) dst[tid + c * 256] = src[tid + c * 256];
        const float4* os = reinterpret_cast<const float4*>(obs + (size_t)r0 * NAGENTS * NOBSV);
        reinterpret_cast<float4*>(&s_o[0][0])[tid] = os[tid];
    }
    __syncthreads();

    #pragma unroll 1
    for (int pp = 0; pp < 2; ++pp) {
        const int p = tid + pp * 256;
        const int row = p >> 5, a = p & 31;

        // f64 mask, bit-exact vs numpy-f64 reference
        unsigned int bits = 0u;
        {
            const double xi = (double)s_o[row][a * 2 + 0] * 2.0;
            const double yi = (double)s_o[row][a * 2 + 1] * 6.0;
            #pragma unroll
            for (int j = 0; j < NAGENTS; ++j) {
                double xj = (double)s_o[row][j * 2 + 0] * 2.0;
                double yj = (double)s_o[row][j * 2 + 1] * 6.0;
                double d = fabs(xi - xj) + fabs(yi - yj);
                if (d > 0.0 && d < 2.0) bits |= (1u << j);
            }
        }
        const float Jv = fmaxf((float)__popc(bits), 1.0f);

        float acc[HXD];
        #pragma unroll
        for (int o = 0; o < HXD; ++o) acc[o] = 0.0f;
        #pragma unroll 4
        for (int j = 0; j < NAGENTS; ++j) {
            const float m = (float)((bits >> j) & 1u);
            const half8* hp = reinterpret_cast<const half8*>(&s_t[row][j * HXD]);
            #pragma unroll
            for (int c = 0; c < 8; ++c) {
                half8 v = hp[c];
                #pragma unroll
                for (int e = 0; e < 8; ++e)
                    acc[c * 8 + e] = fmaf(m, (float)v[e], acc[c * 8 + e]);
            }
        }
        half8* dst = reinterpret_cast<half8*>(
            cms + ((size_t)(r0 + row) * NAGENTS + a) * HXD);
        #pragma unroll
        for (int c = 0; c < 8; ++c) {
            half8 ov;
            #pragma unroll
            for (int e = 0; e < 8; ++e) ov[e] = (_Float16)(acc[c * 8 + e] / Jv);
            dst[c] = ov;
        }
    }
}

// ==================== Kernel 3: comm MLP + decoder ====================
// grid (B/128, 32). Wc LDS-resident; comm_input tile f16 in LDS.
// lane = lb*8+og; rows = wave*32 + rr*8 + lb (lb fastest -> bank spread).
#define CIST 136   // s_ci row stride in halves (128 + 8 pad, 16B-aligned)
__global__ __launch_bounds__(256, 2) void k3_head(
    const _Float16* __restrict__ hid, const _Float16* __restrict__ cms,
    const float* __restrict__ Wc, const float* __restrict__ bc,
    const float* __restrict__ Wd, const float* __restrict__ bd,
    float* __restrict__ out)
{
    __shared__ float    s_wc[2 * HXD][HXD];    // 32 KB
    __shared__ float    s_bc[HXD];
    __shared__ float    s_wd[HXD][9];
    __shared__ float    s_bd[8];
    __shared__ _Float16 s_ci[128][CIST];       // 34 KB

    const int a  = blockIdx.y;
    const int r0 = blockIdx.x * 128;
    const int tid = threadIdx.x;

    {
        const float4* wcs = reinterpret_cast<const float4*>(Wc + (size_t)a * (2 * HXD * HXD));
        float4* wcd = reinterpret_cast<float4*>(&s_wc[0][0]);
        #pragma unroll
        for (int c = 0; c < 8; ++c) wcd[tid + c * 256] = wcs[tid + c * 256];
        if (tid < HXD) {
            s_bc[tid] = bc[a * HXD + tid];
            #pragma unroll
            for (int o = 0; o < NACTD; ++o)
                s_wd[tid][o] = Wd[(size_t)a * (HXD * NACTD) + tid * NACTD + o];
        } else if (tid < HXD + NACTD) {
            s_bd[tid - HXD] = bd[a * NACTD + (tid - HXD)];
        }
        #pragma unroll
        for (int c = 0; c < 8; ++c) {
            const int idx = tid + c * 256;          // 0..2047
            const int row = idx >> 4, h8 = idx & 15;
            const size_t base = ((size_t)(r0 + row) * NAGENTS + a) * HXD;
            half8 v = (h8 < 8)
                ? reinterpret_cast<const half8*>(hid + base)[h8]
                : reinterpret_cast<const half8*>(cms + base)[h8 - 8];
            reinterpret_cast<half8*>(&s_ci[row][0])[h8] = v;
        }
    }
    __syncthreads();

    const int wv = tid >> 6, lane = tid & 63;
    const int og = lane & 7, lb = lane >> 3;

    float acc[4][8];
    #pragma unroll
    for (int rr = 0; rr < 4; ++rr)
        #pragma unroll
        for (int i = 0; i < 8; ++i) acc[rr][i] = s_bc[og * 8 + i];

    #pragma unroll 2
    for (int kc = 0; kc < 16; ++kc) {
        float ci[4][8];
        #pragma unroll
        for (int rr = 0; rr < 4; ++rr) {
            const int row = wv * 32 + rr * 8 + lb;
            half8 v = *reinterpret_cast<const half8*>(&s_ci[row][kc * 8]);
            #pragma unroll
            for (int e = 0; e < 8; ++e) ci[rr][e] = (float)v[e];
        }
        #pragma unroll
        for (int kk = 0; kk < 8; ++kk) {
            const int k = kc * 8 + kk;
            const float4 wv0 = *reinterpret_cast<const float4*>(&s_wc[k][og * 8]);
            const float4 wv1 = *reinterpret_cast<const float4*>(&s_wc[k][og * 8 + 4]);
            #pragma unroll
            for (int rr = 0; rr < 4; ++rr) {
                const float c0 = ci[rr][kk];
                acc[rr][0] = fmaf(c0, wv0.x, acc[rr][0]);
                acc[rr][1] = fmaf(c0, wv0.y, acc[rr][1]);
                acc[rr][2] = fmaf(c0, wv0.z, acc[rr][2]);
                acc[rr][3] = fmaf(c0, wv0.w, acc[rr][3]);
                acc[rr][4] = fmaf(c0, wv1.x, acc[rr][4]);
                acc[rr][5] = fmaf(c0, wv1.y, acc[rr][5]);
                acc[rr][6] = fmaf(c0, wv1.z, acc[rr][6]);
                acc[rr][7] = fmaf(c0, wv1.w, acc[rr][7]);
            }
        }
    }

    // tanh + decoder partial + og-reduce + store
    #pragma unroll 1
    for (int rr = 0; rr < 4; ++rr) {
        float qv[NACTD];
        #pragma unroll
        for (int o = 0; o < NACTD; ++o) qv[o] = 0.0f;
        #pragma unroll
        for (int i = 0; i < 8; ++i) {
            const float h2 = tanhf(acc[rr][i]);
            #pragma unroll
            for (int o = 0; o < NACTD; ++o)
                qv[o] = fmaf(h2, s_wd[og * 8 + i][o], qv[o]);
        }
        #pragma unroll
        for (int o = 0; o < NACTD; ++o) {
            qv[o] += __shfl_xor(qv[o], 1, 64);
            qv[o] += __shfl_xor(qv[o], 2, 64);
            qv[o] += __shfl_xor(qv[o], 4, 64);
        }
        if (og == 0) {
            const int row = wv * 32 + rr * 8 + lb;
            float* op = out + ((size_t)(r0 + row) * NAGENTS + a) * NACTD;
            #pragma unroll
            for (int o = 0; o < NACTD; ++o) op[o] = qv[o] + s_bd[o];
        }
    }
}

// ================= Fallback: round-6 fused kernel (991 us, passed) =================
#define TBATCH  8
#define NWAVES  4
#define BFST    2056
#define HROWST  132
__global__ __launch_bounds__(256, 3) void qnet_fused_fb(
    const float* __restrict__ obs,
    const float* __restrict__ W1, const float* __restrict__ b1,
    const float* __restrict__ W2, const float* __restrict__ b2,
    const float* __restrict__ Wc, const float* __restrict__ bc,
    const float* __restrict__ Wd, const float* __restrict__ bd,
    float* __restrict__ out)
{
    __shared__ float    s_obs[TBATCH][NAGENTS * 2 + 2];
    __shared__ _Float16 s_hid[TBATCH * BFST];
    __shared__ float    s_h[NWAVES][TBATCH][HROWST];

    const int tid  = threadIdx.x;
    const int wave = tid >> 6;
    const int lane = tid & 63;
    const int lb   = lane & 7;
    const int og   = lane >> 3;
    const int b0   = blockIdx.x * TBATCH;

    {
        const float2* src = reinterpret_cast<const float2*>(obs + (size_t)b0 * (NAGENTS * NOBSV));
        float2 v = src[tid];
        s_obs[tid >> 5][(tid & 31) * 2 + 0] = v.x;
        s_obs[tid >> 5][(tid & 31) * 2 + 1] = v.y;
    }
    __syncthreads();

    const int p_a = tid >> 3;
    const int p_b = tid & 7;
    unsigned int bits = 0u;
    float Jf;
    {
        const double xi = (double)s_obs[p_b][p_a * 2 + 0] * 2.0;
        const double yi = (double)s_obs[p_b][p_a * 2 + 1] * 6.0;
        #pragma unroll
        for (int j = 0; j < NAGENTS; ++j) {
            double xj = (double)s_obs[p_b][j * 2 + 0] * 2.0;
            double yj = (double)s_obs[p_b][j * 2 + 1] * 6.0;
            double d = fabs(xi - xj) + fabs(yi - yj);
            if (d > 0.0 && d < 2.0) bits |= (1u << j);
        }
        Jf = fmaxf((float)__popc(bits), 1.0f);
    }

    #pragma unroll 1
    for (int ai = 0; ai < 8; ++ai) {
        const int a = wave * 8 + ai;
        const float o0 = s_obs[lb][a * 2 + 0];
        const float o1 = s_obs[lb][a * 2 + 1];
        {
            const float* __restrict__ w1a = W1 + a * (NOBSV * H1D) + og * 16;
            const float* __restrict__ w1b = w1a + H1D;
            const float* __restrict__ b1p = b1 + a * H1D + og * 16;
            float* hdst = &s_h[wave][lb][og * 16];
            #pragma unroll
            for (int c = 0; c < 4; ++c) {
                float4 wa = *reinterpret_cast<const float4*>(w1a + 4 * c);
                float4 wb = *reinterpret_cast<const float4*>(w1b + 4 * c);
                float4 bv = *reinterpret_cast<const float4*>(b1p + 4 * c);
                float4 hv;
                hv.x = fmaxf(fmaf(o1, wb.x, fmaf(o0, wa.x, bv.x)), 0.0f);
                hv.y = fmaxf(fmaf(o1, wb.y, fmaf(o0, wa.y, bv.y)), 0.0f);
                hv.z = fmaxf(fmaf(o1, wb.z, fmaf(o0, wa.z, bv.z)), 0.0f);
                hv.w = fmaxf(fmaf(o1, wb.w, fmaf(o0, wa.w, bv.w)), 0.0f);
                *reinterpret_cast<float4*>(hdst + 4 * c) = hv;
            }
        }
        asm volatile("s_waitcnt lgkmcnt(0)" ::: "memory");
        __builtin_amdgcn_sched_barrier(0);

        const float* __restrict__ w2p = W2 + a * (H1D * HXD) + og * 8;
        const float* __restrict__ b2p = b2 + a * HXD + og * 8;
        float acc[8];
        {
            float4 bv0 = *reinterpret_cast<const float4*>(b2p + 0);
            float4 bv1 = *reinterpret_cast<const float4*>(b2p + 4);
            acc[0] = bv0.x; acc[1] = bv0.y; acc[2] = bv0.z; acc[3] = bv0.w;
            acc[4] = bv1.x; acc[5] = bv1.y; acc[6] = bv1.z; acc[7] = bv1.w;
        }
        const float* hsrc = &s_h[wave][lb][0];
        #pragma unroll 8
        for (int k = 0; k < H1D; ++k) {
            const float hv = hsrc[k];
            const float* wr = w2p + k * HXD;
            float4 wv0 = *reinterpret_cast<const float4*>(wr + 0);
            float4 wv1 = *reinterpret_cast<const float4*>(wr + 4);
            acc[0] = fmaf(hv, wv0.x, acc[0]);
            acc[1] = fmaf(hv, wv0.y, acc[1]);
            acc[2] = fmaf(hv, wv0.z, acc[2]);
            acc[3] = fmaf(hv, wv0.w, acc[3]);
            acc[4] = fmaf(hv, wv1.x, acc[4]);
            acc[5] = fmaf(hv, wv1.y, acc[5]);
            acc[6] = fmaf(hv, wv1.z, acc[6]);
            acc[7] = fmaf(hv, wv1.w, acc[7]);
        }
        half8 hh;
        #pragma unroll
        for (int i = 0; i < 8; ++i) hh[i] = (_Float16)fmaxf(acc[i], 0.0f);
        *reinterpret_cast<half8*>(&s_hid[lb * BFST + a * HXD + og * 8]) = hh;
    }
    __syncthreads();

    #pragma unroll 1
    for (int ai = 0; ai < 8; ++ai) {
        const int a = wave * 8 + ai;
        const int srcm = ai * 8 + lb;
        const unsigned int mbits = (unsigned int)__shfl((int)bits, srcm, 64);
        const float Jv = __shfl(Jf, srcm, 64);

        float cm8[8];
        #pragma unroll
        for (int i = 0; i < 8; ++i) cm8[i] = 0.0f;
        {
            const _Float16* hrow = &s_hid[lb * BFST + og * 8];
            #pragma unroll 8
            for (int j = 0; j < NAGENTS; ++j) {
                const float m = (float)((mbits >> j) & 1u);
                half8 v = *reinterpret_cast<const half8*>(hrow + j * HXD);
                cm8[0] = fmaf(m, (float)v[0], cm8[0]);
                cm8[1] = fmaf(m, (float)v[1], cm8[1]);
                cm8[2] = fmaf(m, (float)v[2], cm8[2]);
                cm8[3] = fmaf(m, (float)v[3], cm8[3]);
                cm8[4] = fmaf(m, (float)v[4], cm8[4]);
                cm8[5] = fmaf(m, (float)v[5], cm8[5]);
                cm8[6] = fmaf(m, (float)v[6], cm8[6]);
                cm8[7] = fmaf(m, (float)v[7], cm8[7]);
            }
        }
        {
            float* cw = &s_h[wave][lb][og * 8];
            *reinterpret_cast<float4*>(cw + 0) =
                make_float4(cm8[0]/Jv, cm8[1]/Jv, cm8[2]/Jv, cm8[3]/Jv);
            *reinterpret_cast<float4*>(cw + 4) =
                make_float4(cm8[4]/Jv, cm8[5]/Jv, cm8[6]/Jv, cm8[7]/Jv);
        }
        asm volatile("s_waitcnt lgkmcnt(0)" ::: "memory");
        __builtin_amdgcn_sched_barrier(0);

        const float* __restrict__ wcp = Wc + a * (2 * HXD * HXD) + og * 8;
        const float* __restrict__ bcp = bc + a * HXD + og * 8;
        float acc[8];
        {
            float4 bv0 = *reinterpret_cast<const float4*>(bcp + 0);
            float4 bv1 = *reinterpret_cast<const float4*>(bcp + 4);
            acc[0] = bv0.x; acc[1] = bv0.y; acc[2] = bv0.z; acc[3] = bv0.w;
            acc[4] = bv1.x; acc[5] = bv1.y; acc[6] = bv1.z; acc[7] = bv1.w;
        }
        const _Float16* hbase = &s_hid[lb * BFST + a * HXD];
        #pragma unroll 8
        for (int k = 0; k < HXD; ++k) {
            const float ci = (float)hbase[k];
            const float* wr = wcp + k * HXD;
            float4 wv0 = *reinterpret_cast<const float4*>(wr + 0);
            float4 wv1 = *reinterpret_cast<const float4*>(wr + 4);
            acc[0] = fmaf(ci, wv0.x, acc[0]);
            acc[1] = fmaf(ci, wv0.y, acc[1]);
            acc[2] = fmaf(ci, wv0.z, acc[2]);
            acc[3] = fmaf(ci, wv0.w, acc[3]);
            acc[4] = fmaf(ci, wv1.x, acc[4]);
            acc[5] = fmaf(ci, wv1.y, acc[5]);
            acc[6] = fmaf(ci, wv1.z, acc[6]);
            acc[7] = fmaf(ci, wv1.w, acc[7]);
        }
        #pragma unroll 8
        for (int k2 = 0; k2 < HXD; ++k2) {
            const float ci = s_h[wave][lb][k2];
            const float* wr = wcp + (HXD + k2) * HXD;
            float4 wv0 = *reinterpret_cast<const float4*>(wr + 0);
            float4 wv1 = *reinterpret_cast<const float4*>(wr + 4);
            acc[0] = fmaf(ci, wv0.x, acc[0]);
            acc[1] = fmaf(ci, wv0.y, acc[1]);
            acc[2] = fmaf(ci, wv0.z, acc[2]);
            acc[3] = fmaf(ci, wv0.w, acc[3]);
            acc[4] = fmaf(ci, wv1.x, acc[4]);
            acc[5] = fmaf(ci, wv1.y, acc[5]);
            acc[6] = fmaf(ci, wv1.z, acc[6]);
            acc[7] = fmaf(ci, wv1.w, acc[7]);
        }
        float qv[NACTD];
        #pragma unroll
        for (int o = 0; o < NACTD; ++o) qv[o] = 0.0f;
        const float* __restrict__ wdp = Wd + a * (HXD * NACTD) + og * 8 * NACTD;
        #pragma unroll
        for (int i = 0; i < 8; ++i) {
            float h2 = tanhf(acc[i]);
            #pragma unroll
            for (int o = 0; o < NACTD; ++o)
                qv[o] = fmaf(h2, wdp[i * NACTD + o], qv[o]);
        }
        #pragma unroll
        for (int o = 0; o < NACTD; ++o) {
            qv[o] += __shfl_xor(qv[o], 8, 64);
            qv[o] += __shfl_xor(qv[o], 16, 64);
            qv[o] += __shfl_xor(qv[o], 32, 64);
        }
        if (og == 0) {
            float* op = out + ((size_t)(b0 + lb) * NAGENTS + a) * NACTD;
            const float* bdp = bd + a * NACTD;
            #pragma unroll
            for (int o = 0; o < NACTD; ++o) op[o] = qv[o] + bdp[o];
        }
    }
}

extern "C" void kernel_launch(void* const* d_in, const int* in_sizes, int n_in,
                              void* d_out, int out_size, void* d_ws, size_t ws_size,
                              hipStream_t stream) {
    (void)out_size;
    if (n_in < 9) return;
    const float* obs = (const float*)d_in[0];
    const float* W1  = (const float*)d_in[1];
    const float* b1v = (const float*)d_in[2];
    const float* W2  = (const float*)d_in[3];
    const float* b2v = (const float*)d_in[4];
    const float* Wc  = (const float*)d_in[5];
    const float* bcv = (const float*)d_in[6];
    const float* Wd  = (const float*)d_in[7];
    const float* bdv = (const float*)d_in[8];
    float* out = (float*)d_out;
    const int Btot = in_sizes[0] / (NAGENTS * NOBSV);  // 16384

    const size_t bufHalves = (size_t)Btot * NAGENTS * HXD;
    const size_t need = bufHalves * 2 /*bytes per half*/ * 2 /*buffers*/;
    if (ws_size >= need && (Btot % 128) == 0) {
        _Float16* hid = (_Float16*)d_ws;
        _Float16* cms = hid + bufHalves;
        dim3 blk(256);
        k1_encoder<<<dim3(Btot / 128, NAGENTS), blk, 0, stream>>>(
            obs, W1, b1v, W2, b2v, hid);
        k2_comms<<<dim3(Btot / 16), blk, 0, stream>>>(obs, hid, cms);
        k3_head<<<dim3(Btot / 128, NAGENTS), blk, 0, stream>>>(
            hid, cms, Wc, bcv, Wd, bdv, out);
    } else {
        qnet_fused_fb<<<dim3(Btot / TBATCH), dim3(256), 0, stream>>>(
            obs, W1, b1v, W2, b2v, Wc, bcv, Wd, bdv, out);
    }
}

// Round 9
// 196.125 us; speedup vs baseline: 103.2654x; 1.6769x over previous
//
#include <hip/hip_runtime.h>

#define NAGENTS 32
#define NOBSV   2
#define H1D     128
#define HXD     64
#define NACTD   5
#define CIST    136   // f16 tile row stride (128 + 8 pad; 272B = 17*16B)

typedef _Float16 h8 __attribute__((ext_vector_type(8)));
typedef float f32x4 __attribute__((ext_vector_type(4)));

// MFMA 16x16x32 f16 fragment layouts (gfx950, guide §3 / m89):
//   A: lane l holds A[l&15][(l>>4)*8 + j], j=0..7
//   B: lane l holds B[(l>>4)*8 + j][l&15]
//   C/D: reg r holds C[(l>>4)*4 + r][l&15]
// Weights are split hi/lo f16 (w = whi + wlo exactly to ~2^-22 rel), both
// multiplied in -> f32-equivalent weight precision.

// ============================ Kernel 1: encoder ============================
// grid (B/128, 32): block = (128 batch rows, agent a).
__global__ __launch_bounds__(256, 2) void k1_encoder(
    const float* __restrict__ obs, const float* __restrict__ W1,
    const float* __restrict__ b1, const float* __restrict__ W2,
    const float* __restrict__ b2, _Float16* __restrict__ hid)
{
    __shared__ _Float16 s_h[128][CIST];     // 34.8 KB  h activations f16
    __shared__ h8       s_wf[2][16][64];    // 32.8 KB  W2 frags hi/lo
    __shared__ float    s_w1a[H1D], s_w1b[H1D], s_b1[H1D], s_b2[HXD];

    const int a   = blockIdx.y;
    const int r0  = blockIdx.x * 128;
    const int tid = threadIdx.x;
    const int wv  = tid >> 6, lane = tid & 63;
    const int l15 = lane & 15, lq = lane >> 4;

    // ---- stage W1/b1/b2 + W2 fragments (hi/lo f16) ----
    {
        const float* w1p = W1 + a * (NOBSV * H1D);
        if (tid < H1D) {
            s_w1a[tid] = w1p[tid];
            s_w1b[tid] = w1p[H1D + tid];
            s_b1[tid]  = b1[a * H1D + tid];
        } else if (tid < H1D + HXD) {
            s_b2[tid - H1D] = b2[a * HXD + (tid - H1D)];
        }
        const float* wsrc = W2 + (size_t)a * (H1D * HXD);
        #pragma unroll
        for (int s4 = 0; s4 < 4; ++s4) {
            const int s  = tid + s4 * 256;       // 0..1023
            const int fi = s >> 6, ln = s & 63;  // frag index, lane slot
            const int k0  = (fi >> 2) * 32 + (ln >> 4) * 8;
            const int col = (fi & 3) * 16 + (ln & 15);
            h8 whi, wlo;
            #pragma unroll
            for (int j = 0; j < 8; ++j) {
                float w = wsrc[(size_t)(k0 + j) * HXD + col];
                _Float16 hi = (_Float16)w;
                whi[j] = hi;
                wlo[j] = (_Float16)(w - (float)hi);
            }
            s_wf[0][fi][ln] = whi;
            s_wf[1][fi][ln] = wlo;
        }
    }
    __syncthreads();

    // ---- cooperative h: thread (row=tid>>1, half=tid&1) computes 64 h vals ----
    {
        const int hrow = tid >> 1, hhalf = tid & 1;
        const float2 ov = *reinterpret_cast<const float2*>(
            obs + ((size_t)(r0 + hrow) * NAGENTS + a) * NOBSV);
        #pragma unroll
        for (int c = 0; c < 8; ++c) {
            h8 hv;
            #pragma unroll
            for (int e = 0; e < 8; ++e) {
                const int k = hhalf * 64 + c * 8 + e;
                float h = fmaxf(fmaf(ov.y, s_w1b[k], fmaf(ov.x, s_w1a[k], s_b1[k])), 0.0f);
                hv[e] = (_Float16)h;
            }
            *reinterpret_cast<h8*>(&s_h[hrow][hhalf * 64 + c * 8]) = hv;
        }
    }
    __syncthreads();

    // ---- MFMA GEMM: rows [wv*32, wv*32+32), all 64 cols ----
    f32x4 acc[2][4];
    #pragma unroll
    for (int m = 0; m < 2; ++m)
        #pragma unroll
        for (int n = 0; n < 4; ++n) {
            const float bv = s_b2[n * 16 + l15];
            acc[m][n] = (f32x4){bv, bv, bv, bv};
        }
    #pragma unroll
    for (int kt = 0; kt < 4; ++kt) {
        h8 af0 = *reinterpret_cast<const h8*>(&s_h[wv * 32 + l15][kt * 32 + lq * 8]);
        h8 af1 = *reinterpret_cast<const h8*>(&s_h[wv * 32 + 16 + l15][kt * 32 + lq * 8]);
        #pragma unroll
        for (int n = 0; n < 4; ++n) {
            h8 bh = s_wf[0][kt * 4 + n][lane];
            h8 bl = s_wf[1][kt * 4 + n][lane];
            acc[0][n] = __builtin_amdgcn_mfma_f32_16x16x32_f16(af0, bh, acc[0][n], 0, 0, 0);
            acc[1][n] = __builtin_amdgcn_mfma_f32_16x16x32_f16(af1, bh, acc[1][n], 0, 0, 0);
            acc[0][n] = __builtin_amdgcn_mfma_f32_16x16x32_f16(af0, bl, acc[0][n], 0, 0, 0);
            acc[1][n] = __builtin_amdgcn_mfma_f32_16x16x32_f16(af1, bl, acc[1][n], 0, 0, 0);
        }
    }
    // ---- epilogue: relu -> f16 store to ws ----
    #pragma unroll
    for (int m = 0; m < 2; ++m)
        #pragma unroll
        for (int r = 0; r < 4; ++r) {
            const int row = wv * 32 + m * 16 + lq * 4 + r;
            _Float16* dst = hid + ((size_t)(r0 + row) * NAGENTS + a) * HXD;
            #pragma unroll
            for (int n = 0; n < 4; ++n)
                dst[n * 16 + l15] = (_Float16)fmaxf(acc[m][n][r], 0.0f);
        }
}

// ========================= Kernel 2: mask + comms (unchanged) =========================
__global__ __launch_bounds__(256, 2) void k2_comms(
    const float* __restrict__ obs, const _Float16* __restrict__ hid,
    _Float16* __restrict__ cms)
{
    __shared__ _Float16 s_t[16][NAGENTS * HXD];
    __shared__ float    s_o[16][NAGENTS * 2];

    const int r0 = blockIdx.x * 16;
    const int tid = threadIdx.x;
    {
        const h8* src = reinterpret_cast<const h8*>(hid + (size_t)r0 * NAGENTS * HXD);
        h8* dst = reinterpret_cast<h8*>(&s_t[0][0]);
        #pragma unroll
        for (int c = 0; c < 16; ++c) dst[tid + c * 256] = src[tid + c * 256];
        const float4* os = reinterpret_cast<const float4*>(obs + (size_t)r0 * NAGENTS * NOBSV);
        reinterpret_cast<float4*>(&s_o[0][0])[tid] = os[tid];
    }
    __syncthreads();

    #pragma unroll 1
    for (int pp = 0; pp < 2; ++pp) {
        const int p = tid + pp * 256;
        const int row = p >> 5, a = p & 31;

        unsigned int bits = 0u;
        {
            const double xi = (double)s_o[row][a * 2 + 0] * 2.0;
            const double yi = (double)s_o[row][a * 2 + 1] * 6.0;
            #pragma unroll
            for (int j = 0; j < NAGENTS; ++j) {
                double xj = (double)s_o[row][j * 2 + 0] * 2.0;
                double yj = (double)s_o[row][j * 2 + 1] * 6.0;
                double d = fabs(xi - xj) + fabs(yi - yj);
                if (d > 0.0 && d < 2.0) bits |= (1u << j);
            }
        }
        const float Jv = fmaxf((float)__popc(bits), 1.0f);

        float acc[HXD];
        #pragma unroll
        for (int o = 0; o < HXD; ++o) acc[o] = 0.0f;
        #pragma unroll 4
        for (int j = 0; j < NAGENTS; ++j) {
            const float m = (float)((bits >> j) & 1u);
            const h8* hp = reinterpret_cast<const h8*>(&s_t[row][j * HXD]);
            #pragma unroll
            for (int c = 0; c < 8; ++c) {
                h8 v = hp[c];
                #pragma unroll
                for (int e = 0; e < 8; ++e)
                    acc[c * 8 + e] = fmaf(m, (float)v[e], acc[c * 8 + e]);
            }
        }
        h8* dst = reinterpret_cast<h8*>(cms + ((size_t)(r0 + row) * NAGENTS + a) * HXD);
        #pragma unroll
        for (int c = 0; c < 8; ++c) {
            h8 ov;
            #pragma unroll
            for (int e = 0; e < 8; ++e) ov[e] = (_Float16)(acc[c * 8 + e] / Jv);
            dst[c] = ov;
        }
    }
}

// ==================== Kernel 3: comm MLP + decoder (MFMA) ====================
__global__ __launch_bounds__(256, 2) void k3_head(
    const _Float16* __restrict__ hid, const _Float16* __restrict__ cms,
    const float* __restrict__ Wc, const float* __restrict__ bc,
    const float* __restrict__ Wd, const float* __restrict__ bd,
    float* __restrict__ out)
{
    __shared__ _Float16 s_ci[128][CIST];    // 34.8 KB
    __shared__ h8       s_wf[2][16][64];    // 32.8 KB Wc frags hi/lo
    __shared__ float    s_wd[HXD][8];
    __shared__ float    s_bc[HXD];
    __shared__ float    s_bd[8];

    const int a   = blockIdx.y;
    const int r0  = blockIdx.x * 128;
    const int tid = threadIdx.x;
    const int wv  = tid >> 6, lane = tid & 63;
    const int l15 = lane & 15, lq = lane >> 4;

    // ---- stage Wc frags (hi/lo), wd/bc/bd, comm_input tile ----
    {
        const float* wsrc = Wc + (size_t)a * (2 * HXD * HXD);
        #pragma unroll
        for (int s4 = 0; s4 < 4; ++s4) {
            const int s  = tid + s4 * 256;
            const int fi = s >> 6, ln = s & 63;
            const int k0  = (fi >> 2) * 32 + (ln >> 4) * 8;
            const int col = (fi & 3) * 16 + (ln & 15);
            h8 whi, wlo;
            #pragma unroll
            for (int j = 0; j < 8; ++j) {
                float w = wsrc[(size_t)(k0 + j) * HXD + col];
                _Float16 hi = (_Float16)w;
                whi[j] = hi;
                wlo[j] = (_Float16)(w - (float)hi);
            }
            s_wf[0][fi][ln] = whi;
            s_wf[1][fi][ln] = wlo;
        }
        if (tid < HXD) {
            s_bc[tid] = bc[a * HXD + tid];
            #pragma unroll
            for (int o = 0; o < NACTD; ++o)
                s_wd[tid][o] = Wd[(size_t)a * (HXD * NACTD) + tid * NACTD + o];
        } else if (tid < HXD + NACTD) {
            s_bd[tid - HXD] = bd[a * NACTD + (tid - HXD)];
        }
        #pragma unroll
        for (int c = 0; c < 8; ++c) {
            const int idx = tid + c * 256;
            const int row = idx >> 4, hi8 = idx & 15;
            const size_t base = ((size_t)(r0 + row) * NAGENTS + a) * HXD;
            h8 v = (hi8 < 8)
                ? reinterpret_cast<const h8*>(hid + base)[hi8]
                : reinterpret_cast<const h8*>(cms + base)[hi8 - 8];
            reinterpret_cast<h8*>(&s_ci[row][0])[hi8] = v;
        }
    }
    __syncthreads();

    // ---- MFMA GEMM ----
    f32x4 acc[2][4];
    #pragma unroll
    for (int m = 0; m < 2; ++m)
        #pragma unroll
        for (int n = 0; n < 4; ++n) {
            const float bv = s_bc[n * 16 + l15];
            acc[m][n] = (f32x4){bv, bv, bv, bv};
        }
    #pragma unroll
    for (int kt = 0; kt < 4; ++kt) {
        h8 af0 = *reinterpret_cast<const h8*>(&s_ci[wv * 32 + l15][kt * 32 + lq * 8]);
        h8 af1 = *reinterpret_cast<const h8*>(&s_ci[wv * 32 + 16 + l15][kt * 32 + lq * 8]);
        #pragma unroll
        for (int n = 0; n < 4; ++n) {
            h8 bh = s_wf[0][kt * 4 + n][lane];
            h8 bl = s_wf[1][kt * 4 + n][lane];
            acc[0][n] = __builtin_amdgcn_mfma_f32_16x16x32_f16(af0, bh, acc[0][n], 0, 0, 0);
            acc[1][n] = __builtin_amdgcn_mfma_f32_16x16x32_f16(af1, bh, acc[1][n], 0, 0, 0);
            acc[0][n] = __builtin_amdgcn_mfma_f32_16x16x32_f16(af0, bl, acc[0][n], 0, 0, 0);
            acc[1][n] = __builtin_amdgcn_mfma_f32_16x16x32_f16(af1, bl, acc[1][n], 0, 0, 0);
        }
    }

    // ---- epilogue: tanh + decoder + 16-lane reduce + store ----
    #pragma unroll
    for (int m = 0; m < 2; ++m)
        #pragma unroll
        for (int r = 0; r < 4; ++r) {
            float qv[NACTD];
            #pragma unroll
            for (int o = 0; o < NACTD; ++o) qv[o] = 0.0f;
            #pragma unroll
            for (int n = 0; n < 4; ++n) {
                const float t = tanhf(acc[m][n][r]);
                const float* wd = s_wd[n * 16 + l15];
                #pragma unroll
                for (int o = 0; o < NACTD; ++o) qv[o] = fmaf(t, wd[o], qv[o]);
            }
            #pragma unroll
            for (int o = 0; o < NACTD; ++o) {
                qv[o] += __shfl_xor(qv[o], 1, 64);
                qv[o] += __shfl_xor(qv[o], 2, 64);
                qv[o] += __shfl_xor(qv[o], 4, 64);
                qv[o] += __shfl_xor(qv[o], 8, 64);
            }
            if (l15 == 0) {
                const int row = wv * 32 + m * 16 + lq * 4 + r;
                float* op = out + ((size_t)(r0 + row) * NAGENTS + a) * NACTD;
                #pragma unroll
                for (int o = 0; o < NACTD; ++o) op[o] = qv[o] + s_bd[o];
            }
        }
}

// ================= Fallback: round-6 fused kernel (passed @991us) =================
#define TBATCH  8
#define NWAVES  4
#define BFST    2056
#define HROWST  132
__global__ __launch_bounds__(256, 3) void qnet_fused_fb(
    const float* __restrict__ obs,
    const float* __restrict__ W1, const float* __restrict__ b1,
    const float* __restrict__ W2, const float* __restrict__ b2,
    const float* __restrict__ Wc, const float* __restrict__ bc,
    const float* __restrict__ Wd, const float* __restrict__ bd,
    float* __restrict__ out)
{
    __shared__ float    s_obs[TBATCH][NAGENTS * 2 + 2];
    __shared__ _Float16 s_hid[TBATCH * BFST];
    __shared__ float    s_h[NWAVES][TBATCH][HROWST];

    const int tid  = threadIdx.x;
    const int wave = tid >> 6;
    const int lane = tid & 63;
    const int lb   = lane & 7;
    const int og   = lane >> 3;
    const int b0   = blockIdx.x * TBATCH;

    {
        const float2* src = reinterpret_cast<const float2*>(obs + (size_t)b0 * (NAGENTS * NOBSV));
        float2 v = src[tid];
        s_obs[tid >> 5][(tid & 31) * 2 + 0] = v.x;
        s_obs[tid >> 5][(tid & 31) * 2 + 1] = v.y;
    }
    __syncthreads();

    const int p_a = tid >> 3;
    const int p_b = tid & 7;
    unsigned int bits = 0u;
    float Jf;
    {
        const double xi = (double)s_obs[p_b][p_a * 2 + 0] * 2.0;
        const double yi = (double)s_obs[p_b][p_a * 2 + 1] * 6.0;
        #pragma unroll
        for (int j = 0; j < NAGENTS; ++j) {
            double xj = (double)s_obs[p_b][j * 2 + 0] * 2.0;
            double yj = (double)s_obs[p_b][j * 2 + 1] * 6.0;
            double d = fabs(xi - xj) + fabs(yi - yj);
            if (d > 0.0 && d < 2.0) bits |= (1u << j);
        }
        Jf = fmaxf((float)__popc(bits), 1.0f);
    }

    #pragma unroll 1
    for (int ai = 0; ai < 8; ++ai) {
        const int a = wave * 8 + ai;
        const float o0 = s_obs[lb][a * 2 + 0];
        const float o1 = s_obs[lb][a * 2 + 1];
        {
            const float* __restrict__ w1a = W1 + a * (NOBSV * H1D) + og * 16;
            const float* __restrict__ w1b = w1a + H1D;
            const float* __restrict__ b1p = b1 + a * H1D + og * 16;
            float* hdst = &s_h[wave][lb][og * 16];
            #pragma unroll
            for (int c = 0; c < 4; ++c) {
                float4 wa = *reinterpret_cast<const float4*>(w1a + 4 * c);
                float4 wb = *reinterpret_cast<const float4*>(w1b + 4 * c);
                float4 bv = *reinterpret_cast<const float4*>(b1p + 4 * c);
                float4 hv;
                hv.x = fmaxf(fmaf(o1, wb.x, fmaf(o0, wa.x, bv.x)), 0.0f);
                hv.y = fmaxf(fmaf(o1, wb.y, fmaf(o0, wa.y, bv.y)), 0.0f);
                hv.z = fmaxf(fmaf(o1, wb.z, fmaf(o0, wa.z, bv.z)), 0.0f);
                hv.w = fmaxf(fmaf(o1, wb.w, fmaf(o0, wa.w, bv.w)), 0.0f);
                *reinterpret_cast<float4*>(hdst + 4 * c) = hv;
            }
        }
        asm volatile("s_waitcnt lgkmcnt(0)" ::: "memory");
        __builtin_amdgcn_sched_barrier(0);

        const float* __restrict__ w2p = W2 + a * (H1D * HXD) + og * 8;
        const float* __restrict__ b2p = b2 + a * HXD + og * 8;
        float acc[8];
        {
            float4 bv0 = *reinterpret_cast<const float4*>(b2p + 0);
            float4 bv1 = *reinterpret_cast<const float4*>(b2p + 4);
            acc[0] = bv0.x; acc[1] = bv0.y; acc[2] = bv0.z; acc[3] = bv0.w;
            acc[4] = bv1.x; acc[5] = bv1.y; acc[6] = bv1.z; acc[7] = bv1.w;
        }
        const float* hsrc = &s_h[wave][lb][0];
        #pragma unroll 8
        for (int k = 0; k < H1D; ++k) {
            const float hv = hsrc[k];
            const float* wr = w2p + k * HXD;
            float4 wv0 = *reinterpret_cast<const float4*>(wr + 0);
            float4 wv1 = *reinterpret_cast<const float4*>(wr + 4);
            acc[0] = fmaf(hv, wv0.x, acc[0]);
            acc[1] = fmaf(hv, wv0.y, acc[1]);
            acc[2] = fmaf(hv, wv0.z, acc[2]);
            acc[3] = fmaf(hv, wv0.w, acc[3]);
            acc[4] = fmaf(hv, wv1.x, acc[4]);
            acc[5] = fmaf(hv, wv1.y, acc[5]);
            acc[6] = fmaf(hv, wv1.z, acc[6]);
            acc[7] = fmaf(hv, wv1.w, acc[7]);
        }
        h8 hh;
        #pragma unroll
        for (int i = 0; i < 8; ++i) hh[i] = (_Float16)fmaxf(acc[i], 0.0f);
        *reinterpret_cast<h8*>(&s_hid[lb * BFST + a * HXD + og * 8]) = hh;
    }
    __syncthreads();

    #pragma unroll 1
    for (int ai = 0; ai < 8; ++ai) {
        const int a = wave * 8 + ai;
        const int srcm = ai * 8 + lb;
        const unsigned int mbits = (unsigned int)__shfl((int)bits, srcm, 64);
        const float Jv = __shfl(Jf, srcm, 64);

        float cm8[8];
        #pragma unroll
        for (int i = 0; i < 8; ++i) cm8[i] = 0.0f;
        {
            const _Float16* hrow = &s_hid[lb * BFST + og * 8];
            #pragma unroll 8
            for (int j = 0; j < NAGENTS; ++j) {
                const float m = (float)((mbits >> j) & 1u);
                h8 v = *reinterpret_cast<const h8*>(hrow + j * HXD);
                cm8[0] = fmaf(m, (float)v[0], cm8[0]);
                cm8[1] = fmaf(m, (float)v[1], cm8[1]);
                cm8[2] = fmaf(m, (float)v[2], cm8[2]);
                cm8[3] = fmaf(m, (float)v[3], cm8[3]);
                cm8[4] = fmaf(m, (float)v[4], cm8[4]);
                cm8[5] = fmaf(m, (float)v[5], cm8[5]);
                cm8[6] = fmaf(m, (float)v[6], cm8[6]);
                cm8[7] = fmaf(m, (float)v[7], cm8[7]);
            }
        }
        {
            float* cw = &s_h[wave][lb][og * 8];
            *reinterpret_cast<float4*>(cw + 0) =
                make_float4(cm8[0]/Jv, cm8[1]/Jv, cm8[2]/Jv, cm8[3]/Jv);
            *reinterpret_cast<float4*>(cw + 4) =
                make_float4(cm8[4]/Jv, cm8[5]/Jv, cm8[6]/Jv, cm8[7]/Jv);
        }
        asm volatile("s_waitcnt lgkmcnt(0)" ::: "memory");
        __builtin_amdgcn_sched_barrier(0);

        const float* __restrict__ wcp = Wc + a * (2 * HXD * HXD) + og * 8;
        const float* __restrict__ bcp = bc + a * HXD + og * 8;
        float acc[8];
        {
            float4 bv0 = *reinterpret_cast<const float4*>(bcp + 0);
            float4 bv1 = *reinterpret_cast<const float4*>(bcp + 4);
            acc[0] = bv0.x; acc[1] = bv0.y; acc[2] = bv0.z; acc[3] = bv0.w;
            acc[4] = bv1.x; acc[5] = bv1.y; acc[6] = bv1.z; acc[7] = bv1.w;
        }
        const _Float16* hbase = &s_hid[lb * BFST + a * HXD];
        #pragma unroll 8
        for (int k = 0; k < HXD; ++k) {
            const float ci = (float)hbase[k];
            const float* wr = wcp + k * HXD;
            float4 wv0 = *reinterpret_cast<const float4*>(wr + 0);
            float4 wv1 = *reinterpret_cast<const float4*>(wr + 4);
            acc[0] = fmaf(ci, wv0.x, acc[0]);
            acc[1] = fmaf(ci, wv0.y, acc[1]);
            acc[2] = fmaf(ci, wv0.z, acc[2]);
            acc[3] = fmaf(ci, wv0.w, acc[3]);
            acc[4] = fmaf(ci, wv1.x, acc[4]);
            acc[5] = fmaf(ci, wv1.y, acc[5]);
            acc[6] = fmaf(ci, wv1.z, acc[6]);
            acc[7] = fmaf(ci, wv1.w, acc[7]);
        }
        #pragma unroll 8
        for (int k2 = 0; k2 < HXD; ++k2) {
            const float ci = s_h[wave][lb][k2];
            const float* wr = wcp + (HXD + k2) * HXD;
            float4 wv0 = *reinterpret_cast<const float4*>(wr + 0);
            float4 wv1 = *reinterpret_cast<const float4*>(wr + 4);
            acc[0] = fmaf(ci, wv0.x, acc[0]);
            acc[1] = fmaf(ci, wv0.y, acc[1]);
            acc[2] = fmaf(ci, wv0.z, acc[2]);
            acc[3] = fmaf(ci, wv0.w, acc[3]);
            acc[4] = fmaf(ci, wv1.x, acc[4]);
            acc[5] = fmaf(ci, wv1.y, acc[5]);
            acc[6] = fmaf(ci, wv1.z, acc[6]);
            acc[7] = fmaf(ci, wv1.w, acc[7]);
        }
        float qv[NACTD];
        #pragma unroll
        for (int o = 0; o < NACTD; ++o) qv[o] = 0.0f;
        const float* __restrict__ wdp = Wd + a * (HXD * NACTD) + og * 8 * NACTD;
        #pragma unroll
        for (int i = 0; i < 8; ++i) {
            float h2 = tanhf(acc[i]);
            #pragma unroll
            for (int o = 0; o < NACTD; ++o)
                qv[o] = fmaf(h2, wdp[i * NACTD + o], qv[o]);
        }
        #pragma unroll
        for (int o = 0; o < NACTD; ++o) {
            qv[o] += __shfl_xor(qv[o], 8, 64);
            qv[o] += __shfl_xor(qv[o], 16, 64);
            qv[o] += __shfl_xor(qv[o], 32, 64);
        }
        if (og == 0) {
            float* op = out + ((size_t)(b0 + lb) * NAGENTS + a) * NACTD;
            const float* bdp = bd + a * NACTD;
            #pragma unroll
            for (int o = 0; o < NACTD; ++o) op[o] = qv[o] + bdp[o];
        }
    }
}

extern "C" void kernel_launch(void* const* d_in, const int* in_sizes, int n_in,
                              void* d_out, int out_size, void* d_ws, size_t ws_size,
                              hipStream_t stream) {
    (void)out_size;
    if (n_in < 9) return;
    const float* obs = (const float*)d_in[0];
    const float* W1  = (const float*)d_in[1];
    const float* b1v = (const float*)d_in[2];
    const float* W2  = (const float*)d_in[3];
    const float* b2v = (const float*)d_in[4];
    const float* Wc  = (const float*)d_in[5];
    const float* bcv = (const float*)d_in[6];
    const float* Wd  = (const float*)d_in[7];
    const float* bdv = (const float*)d_in[8];
    float* out = (float*)d_out;
    const int Btot = in_sizes[0] / (NAGENTS * NOBSV);  // 16384

    const size_t bufHalves = (size_t)Btot * NAGENTS * HXD;
    const size_t need = bufHalves * 2 * 2;
    if (ws_size >= need && (Btot % 128) == 0) {
        _Float16* hid = (_Float16*)d_ws;
        _Float16* cms = hid + bufHalves;
        dim3 blk(256);
        k1_encoder<<<dim3(Btot / 128, NAGENTS), blk, 0, stream>>>(
            obs, W1, b1v, W2, b2v, hid);
        k2_comms<<<dim3(Btot / 16), blk, 0, stream>>>(obs, hid, cms);
        k3_head<<<dim3(Btot / 128, NAGENTS), blk, 0, stream>>>(
            hid, cms, Wc, bcv, Wd, bdv, out);
    } else {
        qnet_fused_fb<<<dim3(Btot / TBATCH), dim3(256), 0, stream>>>(
            obs, W1, b1v, W2, b2v, Wc, bcv, Wd, bdv, out);
    }
}

// Round 10
// 145.606 us; speedup vs baseline: 139.0943x; 1.3470x over previous
//
#include <hip/hip_runtime.h>

#define NAGENTS 32
#define NOBSV   2
#define H1D     128
#define HXD     64
#define NACTD   5
#define CIST    136   // f16 tile row stride (128 + 8 pad)

typedef _Float16 h8 __attribute__((ext_vector_type(8)));
typedef float f32x4 __attribute__((ext_vector_type(4)));

// MFMA 16x16x32 f16 layouts (validated by rounds 8-9 passing):
//   A: lane l holds A[l&15][(l>>4)*8 + j]
//   B: lane l holds B[(l>>4)*8 + j][l&15]
//   D: reg r holds D[(l>>4)*4 + r][l&15]

// ================= Kernel 0: weight fragment prep (per agent, once) =================
// wfrag layout: [(mat*32 + a)*2 + part][1024 slots] h8, slot = fi*64 + ln.
__global__ __launch_bounds__(256, 4) void k0_prep(
    const float* __restrict__ W2, const float* __restrict__ Wc,
    h8* __restrict__ wfrag)
{
    const int a = blockIdx.x;
    const int tid = threadIdx.x;
    #pragma unroll
    for (int mat = 0; mat < 2; ++mat) {
        const float* src = (mat == 0 ? W2 : Wc) + (size_t)a * (H1D * HXD);
        h8* dhi = wfrag + ((size_t)(mat * NAGENTS + a) * 2 + 0) * 1024;
        h8* dlo = wfrag + ((size_t)(mat * NAGENTS + a) * 2 + 1) * 1024;
        #pragma unroll
        for (int s4 = 0; s4 < 4; ++s4) {
            const int s  = tid + s4 * 256;
            const int fi = s >> 6, ln = s & 63;
            const int k0  = (fi >> 2) * 32 + (ln >> 4) * 8;
            const int col = (fi & 3) * 16 + (ln & 15);
            h8 whi, wlo;
            #pragma unroll
            for (int j = 0; j < 8; ++j) {
                float w = src[(size_t)(k0 + j) * HXD + col];
                _Float16 hi = (_Float16)w;
                whi[j] = hi;
                wlo[j] = (_Float16)(w - (float)hi);
            }
            dhi[s] = whi;
            dlo[s] = wlo;
        }
    }
}

// ============================ Kernel 1: encoder ============================
__global__ __launch_bounds__(256, 2) void k1_encoder(
    const float* __restrict__ obs, const float* __restrict__ W1,
    const float* __restrict__ b1, const float* __restrict__ W2,
    const float* __restrict__ b2, _Float16* __restrict__ hid,
    const h8* __restrict__ wfrag)
{
    __shared__ _Float16 s_h[128][CIST];
    __shared__ h8       s_wf[2][16][64];
    __shared__ float    s_w1a[H1D], s_w1b[H1D], s_b1[H1D], s_b2[HXD];

    const int a   = blockIdx.y;
    const int r0  = blockIdx.x * 128;
    const int tid = threadIdx.x;
    const int wv  = tid >> 6, lane = tid & 63;
    const int l15 = lane & 15, lq = lane >> 4;

    {
        const float* w1p = W1 + a * (NOBSV * H1D);
        if (tid < H1D) {
            s_w1a[tid] = w1p[tid];
            s_w1b[tid] = w1p[H1D + tid];
            s_b1[tid]  = b1[a * H1D + tid];
        } else if (tid < H1D + HXD) {
            s_b2[tid - H1D] = b2[a * HXD + (tid - H1D)];
        }
        if (wfrag) {
            const h8* srcf = wfrag + (size_t)a * 2048;
            h8* dstf = &s_wf[0][0][0];
            #pragma unroll
            for (int c = 0; c < 8; ++c) dstf[tid + c * 256] = srcf[tid + c * 256];
        } else {
            const float* wsrc = W2 + (size_t)a * (H1D * HXD);
            #pragma unroll
            for (int s4 = 0; s4 < 4; ++s4) {
                const int s  = tid + s4 * 256;
                const int fi = s >> 6, ln = s & 63;
                const int k0  = (fi >> 2) * 32 + (ln >> 4) * 8;
                const int col = (fi & 3) * 16 + (ln & 15);
                h8 whi, wlo;
                #pragma unroll
                for (int j = 0; j < 8; ++j) {
                    float w = wsrc[(size_t)(k0 + j) * HXD + col];
                    _Float16 hi = (_Float16)w;
                    whi[j] = hi;
                    wlo[j] = (_Float16)(w - (float)hi);
                }
                s_wf[0][fi][ln] = whi;
                s_wf[1][fi][ln] = wlo;
            }
        }
    }
    __syncthreads();

    {
        const int hrow = tid >> 1, hhalf = tid & 1;
        const float2 ov = *reinterpret_cast<const float2*>(
            obs + ((size_t)(r0 + hrow) * NAGENTS + a) * NOBSV);
        #pragma unroll
        for (int c = 0; c < 8; ++c) {
            h8 hv;
            #pragma unroll
            for (int e = 0; e < 8; ++e) {
                const int k = hhalf * 64 + c * 8 + e;
                float h = fmaxf(fmaf(ov.y, s_w1b[k], fmaf(ov.x, s_w1a[k], s_b1[k])), 0.0f);
                hv[e] = (_Float16)h;
            }
            *reinterpret_cast<h8*>(&s_h[hrow][hhalf * 64 + c * 8]) = hv;
        }
    }
    __syncthreads();

    f32x4 acc[2][4];
    #pragma unroll
    for (int m = 0; m < 2; ++m)
        #pragma unroll
        for (int n = 0; n < 4; ++n) {
            const float bv = s_b2[n * 16 + l15];
            acc[m][n] = (f32x4){bv, bv, bv, bv};
        }
    #pragma unroll
    for (int kt = 0; kt < 4; ++kt) {
        h8 af0 = *reinterpret_cast<const h8*>(&s_h[wv * 32 + l15][kt * 32 + lq * 8]);
        h8 af1 = *reinterpret_cast<const h8*>(&s_h[wv * 32 + 16 + l15][kt * 32 + lq * 8]);
        #pragma unroll
        for (int n = 0; n < 4; ++n) {
            h8 bh = s_wf[0][kt * 4 + n][lane];
            h8 bl = s_wf[1][kt * 4 + n][lane];
            acc[0][n] = __builtin_amdgcn_mfma_f32_16x16x32_f16(af0, bh, acc[0][n], 0, 0, 0);
            acc[1][n] = __builtin_amdgcn_mfma_f32_16x16x32_f16(af1, bh, acc[1][n], 0, 0, 0);
            acc[0][n] = __builtin_amdgcn_mfma_f32_16x16x32_f16(af0, bl, acc[0][n], 0, 0, 0);
            acc[1][n] = __builtin_amdgcn_mfma_f32_16x16x32_f16(af1, bl, acc[1][n], 0, 0, 0);
        }
    }
    #pragma unroll
    for (int m = 0; m < 2; ++m)
        #pragma unroll
        for (int r = 0; r < 4; ++r) {
            const int row = wv * 32 + m * 16 + lq * 4 + r;
            _Float16* dst = hid + ((size_t)(r0 + row) * NAGENTS + a) * HXD;
            #pragma unroll
            for (int n = 0; n < 4; ++n)
                dst[n * 16 + l15] = (_Float16)fmaxf(acc[m][n][r], 0.0f);
        }
}

// ========================= Kernel 2: mask + comms (MFMA) =========================
// grid (B/8). 8 rows/block; wave w owns rows 2w, 2w+1 (stage->compute wave-private).
__global__ __launch_bounds__(256, 2) void k2_comms(
    const float* __restrict__ obs, const _Float16* __restrict__ hid,
    _Float16* __restrict__ cms)
{
    __shared__ __align__(16) _Float16 s_tt[8][64][40];  // hidden transposed [o][j]
    __shared__ __align__(16) _Float16 s_m[8][32][40];   // mask f16 [a][j]
    __shared__ float s_o[8][66];
    __shared__ float s_J[8][32];

    const int r0  = blockIdx.x * 8;
    const int tid = threadIdx.x;
    const int wv  = tid >> 6, lane = tid & 63;
    const int l15 = lane & 15, lq = lane >> 4;

    // stage obs (8 rows x 64 floats)
    if (tid < 128) {
        const float4 v = reinterpret_cast<const float4*>(obs + (size_t)r0 * NAGENTS * NOBSV)[tid];
        const int row = tid >> 4, seg = tid & 15;
        *reinterpret_cast<float4*>(&s_o[row][seg * 4]) = v;
    }
    __syncthreads();

    // per-wave staging: thread (row = tid>>5, u = tid&31)
    const int row = tid >> 5;   // block-local row, == wv*2 + ((tid>>5)&1)
    const int u   = tid & 31;

    // (a) transposed hidden: u = agent j; load 64 o-values, scatter to s_tt[row][o][j]
    {
        const h8* src = reinterpret_cast<const h8*>(
            hid + ((size_t)(r0 + row) * NAGENTS + u) * HXD);
        #pragma unroll
        for (int c = 0; c < 8; ++c) {
            h8 v = src[c];
            #pragma unroll
            for (int e = 0; e < 8; ++e) s_tt[row][c * 8 + e][u] = v[e];
        }
    }
    // (b) mask row: u = agent a; f64 math bit-matches numpy-f64 reference
    {
        unsigned int bits = 0u;
        const double xi = (double)s_o[row][u * 2 + 0] * 2.0;
        const double yi = (double)s_o[row][u * 2 + 1] * 6.0;
        #pragma unroll
        for (int j = 0; j < NAGENTS; ++j) {
            double xj = (double)s_o[row][j * 2 + 0] * 2.0;
            double yj = (double)s_o[row][j * 2 + 1] * 6.0;
            double d = fabs(xi - xj) + fabs(yi - yj);
            if (d > 0.0 && d < 2.0) bits |= (1u << j);
        }
        s_J[row][u] = fmaxf((float)__popc(bits), 1.0f);
        #pragma unroll
        for (int c = 0; c < 4; ++c) {
            h8 mv;
            #pragma unroll
            for (int e = 0; e < 8; ++e)
                mv[e] = ((bits >> (c * 8 + e)) & 1u) ? (_Float16)1.0f : (_Float16)0.0f;
            *reinterpret_cast<h8*>(&s_m[row][u][c * 8]) = mv;
        }
    }
    asm volatile("s_waitcnt lgkmcnt(0)" ::: "memory");
    __builtin_amdgcn_sched_barrier(0);

    // per-wave MFMA: rows 2wv, 2wv+1 ; D[a][o] = mask[32x32] @ hiddenT
    #pragma unroll
    for (int rr = 0; rr < 2; ++rr) {
        const int rw = wv * 2 + rr;
        h8 a0 = *reinterpret_cast<const h8*>(&s_m[rw][l15][lq * 8]);
        h8 a1 = *reinterpret_cast<const h8*>(&s_m[rw][16 + l15][lq * 8]);
        f32x4 acc[2][4];
        #pragma unroll
        for (int m = 0; m < 2; ++m)
            #pragma unroll
            for (int n = 0; n < 4; ++n) acc[m][n] = (f32x4){0.f, 0.f, 0.f, 0.f};
        #pragma unroll
        for (int n = 0; n < 4; ++n) {
            h8 b = *reinterpret_cast<const h8*>(&s_tt[rw][n * 16 + l15][lq * 8]);
            acc[0][n] = __builtin_amdgcn_mfma_f32_16x16x32_f16(a0, b, acc[0][n], 0, 0, 0);
            acc[1][n] = __builtin_amdgcn_mfma_f32_16x16x32_f16(a1, b, acc[1][n], 0, 0, 0);
        }
        #pragma unroll
        for (int m = 0; m < 2; ++m)
            #pragma unroll
            for (int r = 0; r < 4; ++r) {
                const int ai = m * 16 + lq * 4 + r;
                const float Jv = s_J[rw][ai];
                _Float16* dst = cms + ((size_t)(r0 + rw) * NAGENTS + ai) * HXD;
                #pragma unroll
                for (int n = 0; n < 4; ++n)
                    dst[n * 16 + l15] = (_Float16)(acc[m][n][r] / Jv);
            }
    }
}

// ==================== Kernel 3: comm MLP + decoder (MFMA) ====================
__global__ __launch_bounds__(256, 2) void k3_head(
    const _Float16* __restrict__ hid, const _Float16* __restrict__ cms,
    const float* __restrict__ Wc, const float* __restrict__ bc,
    const float* __restrict__ Wd, const float* __restrict__ bd,
    float* __restrict__ out, const h8* __restrict__ wfrag)
{
    __shared__ _Float16 s_ci[128][CIST];
    __shared__ h8       s_wf[2][16][64];
    __shared__ float    s_wd[HXD][8];
    __shared__ float    s_bc[HXD];
    __shared__ float    s_bd[8];

    const int a   = blockIdx.y;
    const int r0  = blockIdx.x * 128;
    const int tid = threadIdx.x;
    const int wv  = tid >> 6, lane = tid & 63;
    const int l15 = lane & 15, lq = lane >> 4;

    {
        if (wfrag) {
            const h8* srcf = wfrag + (size_t)(NAGENTS + a) * 2048;
            h8* dstf = &s_wf[0][0][0];
            #pragma unroll
            for (int c = 0; c < 8; ++c) dstf[tid + c * 256] = srcf[tid + c * 256];
        } else {
            const float* wsrc = Wc + (size_t)a * (2 * HXD * HXD);
            #pragma unroll
            for (int s4 = 0; s4 < 4; ++s4) {
                const int s  = tid + s4 * 256;
                const int fi = s >> 6, ln = s & 63;
                const int k0  = (fi >> 2) * 32 + (ln >> 4) * 8;
                const int col = (fi & 3) * 16 + (ln & 15);
                h8 whi, wlo;
                #pragma unroll
                for (int j = 0; j < 8; ++j) {
                    float w = wsrc[(size_t)(k0 + j) * HXD + col];
                    _Float16 hi = (_Float16)w;
                    whi[j] = hi;
                    wlo[j] = (_Float16)(w - (float)hi);
                }
                s_wf[0][fi][ln] = whi;
                s_wf[1][fi][ln] = wlo;
            }
        }
        if (tid < HXD) {
            s_bc[tid] = bc[a * HXD + tid];
            #pragma unroll
            for (int o = 0; o < NACTD; ++o)
                s_wd[tid][o] = Wd[(size_t)a * (HXD * NACTD) + tid * NACTD + o];
        } else if (tid < HXD + NACTD) {
            s_bd[tid - HXD] = bd[a * NACTD + (tid - HXD)];
        }
        #pragma unroll
        for (int c = 0; c < 8; ++c) {
            const int idx = tid + c * 256;
            const int row = idx >> 4, hi8 = idx & 15;
            const size_t base = ((size_t)(r0 + row) * NAGENTS + a) * HXD;
            h8 v = (hi8 < 8)
                ? reinterpret_cast<const h8*>(hid + base)[hi8]
                : reinterpret_cast<const h8*>(cms + base)[hi8 - 8];
            reinterpret_cast<h8*>(&s_ci[row][0])[hi8] = v;
        }
    }
    __syncthreads();

    f32x4 acc[2][4];
    #pragma unroll
    for (int m = 0; m < 2; ++m)
        #pragma unroll
        for (int n = 0; n < 4; ++n) {
            const float bv = s_bc[n * 16 + l15];
            acc[m][n] = (f32x4){bv, bv, bv, bv};
        }
    #pragma unroll
    for (int kt = 0; kt < 4; ++kt) {
        h8 af0 = *reinterpret_cast<const h8*>(&s_ci[wv * 32 + l15][kt * 32 + lq * 8]);
        h8 af1 = *reinterpret_cast<const h8*>(&s_ci[wv * 32 + 16 + l15][kt * 32 + lq * 8]);
        #pragma unroll
        for (int n = 0; n < 4; ++n) {
            h8 bh = s_wf[0][kt * 4 + n][lane];
            h8 bl = s_wf[1][kt * 4 + n][lane];
            acc[0][n] = __builtin_amdgcn_mfma_f32_16x16x32_f16(af0, bh, acc[0][n], 0, 0, 0);
            acc[1][n] = __builtin_amdgcn_mfma_f32_16x16x32_f16(af1, bh, acc[1][n], 0, 0, 0);
            acc[0][n] = __builtin_amdgcn_mfma_f32_16x16x32_f16(af0, bl, acc[0][n], 0, 0, 0);
            acc[1][n] = __builtin_amdgcn_mfma_f32_16x16x32_f16(af1, bl, acc[1][n], 0, 0, 0);
        }
    }

    #pragma unroll
    for (int m = 0; m < 2; ++m)
        #pragma unroll
        for (int r = 0; r < 4; ++r) {
            float qv[NACTD];
            #pragma unroll
            for (int o = 0; o < NACTD; ++o) qv[o] = 0.0f;
            #pragma unroll
            for (int n = 0; n < 4; ++n) {
                const float t = tanhf(acc[m][n][r]);
                const float* wd = s_wd[n * 16 + l15];
                #pragma unroll
                for (int o = 0; o < NACTD; ++o) qv[o] = fmaf(t, wd[o], qv[o]);
            }
            #pragma unroll
            for (int o = 0; o < NACTD; ++o) {
                qv[o] += __shfl_xor(qv[o], 1, 64);
                qv[o] += __shfl_xor(qv[o], 2, 64);
                qv[o] += __shfl_xor(qv[o], 4, 64);
                qv[o] += __shfl_xor(qv[o], 8, 64);
            }
            if (l15 == 0) {
                const int row = wv * 32 + m * 16 + lq * 4 + r;
                float* op = out + ((size_t)(r0 + row) * NAGENTS + a) * NACTD;
                #pragma unroll
                for (int o = 0; o < NACTD; ++o) op[o] = qv[o] + s_bd[o];
            }
        }
}

// ================= Fallback: round-6 fused kernel (passed @991us) =================
#define TBATCH  8
#define NWAVES  4
#define BFST    2056
#define HROWST  132
__global__ __launch_bounds__(256, 3) void qnet_fused_fb(
    const float* __restrict__ obs,
    const float* __restrict__ W1, const float* __restrict__ b1,
    const float* __restrict__ W2, const float* __restrict__ b2,
    const float* __restrict__ Wc, const float* __restrict__ bc,
    const float* __restrict__ Wd, const float* __restrict__ bd,
    float* __restrict__ out)
{
    __shared__ float    s_obs[TBATCH][NAGENTS * 2 + 2];
    __shared__ _Float16 s_hid[TBATCH * BFST];
    __shared__ float    s_h[NWAVES][TBATCH][HROWST];

    const int tid  = threadIdx.x;
    const int wave = tid >> 6;
    const int lane = tid & 63;
    const int lb   = lane & 7;
    const int og   = lane >> 3;
    const int b0   = blockIdx.x * TBATCH;

    {
        const float2* src = reinterpret_cast<const float2*>(obs + (size_t)b0 * (NAGENTS * NOBSV));
        float2 v = src[tid];
        s_obs[tid >> 5][(tid & 31) * 2 + 0] = v.x;
        s_obs[tid >> 5][(tid & 31) * 2 + 1] = v.y;
    }
    __syncthreads();

    const int p_a = tid >> 3;
    const int p_b = tid & 7;
    unsigned int bits = 0u;
    float Jf;
    {
        const double xi = (double)s_obs[p_b][p_a * 2 + 0] * 2.0;
        const double yi = (double)s_obs[p_b][p_a * 2 + 1] * 6.0;
        #pragma unroll
        for (int j = 0; j < NAGENTS; ++j) {
            double xj = (double)s_obs[p_b][j * 2 + 0] * 2.0;
            double yj = (double)s_obs[p_b][j * 2 + 1] * 6.0;
            double d = fabs(xi - xj) + fabs(yi - yj);
            if (d > 0.0 && d < 2.0) bits |= (1u << j);
        }
        Jf = fmaxf((float)__popc(bits), 1.0f);
    }

    #pragma unroll 1
    for (int ai = 0; ai < 8; ++ai) {
        const int a = wave * 8 + ai;
        const float o0 = s_obs[lb][a * 2 + 0];
        const float o1 = s_obs[lb][a * 2 + 1];
        {
            const float* __restrict__ w1a = W1 + a * (NOBSV * H1D) + og * 16;
            const float* __restrict__ w1b = w1a + H1D;
            const float* __restrict__ b1p = b1 + a * H1D + og * 16;
            float* hdst = &s_h[wave][lb][og * 16];
            #pragma unroll
            for (int c = 0; c < 4; ++c) {
                float4 wa = *reinterpret_cast<const float4*>(w1a + 4 * c);
                float4 wb = *reinterpret_cast<const float4*>(w1b + 4 * c);
                float4 bv = *reinterpret_cast<const float4*>(b1p + 4 * c);
                float4 hv;
                hv.x = fmaxf(fmaf(o1, wb.x, fmaf(o0, wa.x, bv.x)), 0.0f);
                hv.y = fmaxf(fmaf(o1, wb.y, fmaf(o0, wa.y, bv.y)), 0.0f);
                hv.z = fmaxf(fmaf(o1, wb.z, fmaf(o0, wa.z, bv.z)), 0.0f);
                hv.w = fmaxf(fmaf(o1, wb.w, fmaf(o0, wa.w, bv.w)), 0.0f);
                *reinterpret_cast<float4*>(hdst + 4 * c) = hv;
            }
        }
        asm volatile("s_waitcnt lgkmcnt(0)" ::: "memory");
        __builtin_amdgcn_sched_barrier(0);

        const float* __restrict__ w2p = W2 + a * (H1D * HXD) + og * 8;
        const float* __restrict__ b2p = b2 + a * HXD + og * 8;
        float acc[8];
        {
            float4 bv0 = *reinterpret_cast<const float4*>(b2p + 0);
            float4 bv1 = *reinterpret_cast<const float4*>(b2p + 4);
            acc[0] = bv0.x; acc[1] = bv0.y; acc[2] = bv0.z; acc[3] = bv0.w;
            acc[4] = bv1.x; acc[5] = bv1.y; acc[6] = bv1.z; acc[7] = bv1.w;
        }
        const float* hsrc = &s_h[wave][lb][0];
        #pragma unroll 8
        for (int k = 0; k < H1D; ++k) {
            const float hv = hsrc[k];
            const float* wr = w2p + k * HXD;
            float4 wv0 = *reinterpret_cast<const float4*>(wr + 0);
            float4 wv1 = *reinterpret_cast<const float4*>(wr + 4);
            acc[0] = fmaf(hv, wv0.x, acc[0]);
            acc[1] = fmaf(hv, wv0.y, acc[1]);
            acc[2] = fmaf(hv, wv0.z, acc[2]);
            acc[3] = fmaf(hv, wv0.w, acc[3]);
            acc[4] = fmaf(hv, wv1.x, acc[4]);
            acc[5] = fmaf(hv, wv1.y, acc[5]);
            acc[6] = fmaf(hv, wv1.z, acc[6]);
            acc[7] = fmaf(hv, wv1.w, acc[7]);
        }
        h8 hh;
        #pragma unroll
        for (int i = 0; i < 8; ++i) hh[i] = (_Float16)fmaxf(acc[i], 0.0f);
        *reinterpret_cast<h8*>(&s_hid[lb * BFST + a * HXD + og * 8]) = hh;
    }
    __syncthreads();

    #pragma unroll 1
    for (int ai = 0; ai < 8; ++ai) {
        const int a = wave * 8 + ai;
        const int srcm = ai * 8 + lb;
        const unsigned int mbits = (unsigned int)__shfl((int)bits, srcm, 64);
        const float Jv = __shfl(Jf, srcm, 64);

        float cm8[8];
        #pragma unroll
        for (int i = 0; i < 8; ++i) cm8[i] = 0.0f;
        {
            const _Float16* hrow = &s_hid[lb * BFST + og * 8];
            #pragma unroll 8
            for (int j = 0; j < NAGENTS; ++j) {
                const float m = (float)((mbits >> j) & 1u);
                h8 v = *reinterpret_cast<const h8*>(hrow + j * HXD);
                cm8[0] = fmaf(m, (float)v[0], cm8[0]);
                cm8[1] = fmaf(m, (float)v[1], cm8[1]);
                cm8[2] = fmaf(m, (float)v[2], cm8[2]);
                cm8[3] = fmaf(m, (float)v[3], cm8[3]);
                cm8[4] = fmaf(m, (float)v[4], cm8[4]);
                cm8[5] = fmaf(m, (float)v[5], cm8[5]);
                cm8[6] = fmaf(m, (float)v[6], cm8[6]);
                cm8[7] = fmaf(m, (float)v[7], cm8[7]);
            }
        }
        {
            float* cw = &s_h[wave][lb][og * 8];
            *reinterpret_cast<float4*>(cw + 0) =
                make_float4(cm8[0]/Jv, cm8[1]/Jv, cm8[2]/Jv, cm8[3]/Jv);
            *reinterpret_cast<float4*>(cw + 4) =
                make_float4(cm8[4]/Jv, cm8[5]/Jv, cm8[6]/Jv, cm8[7]/Jv);
        }
        asm volatile("s_waitcnt lgkmcnt(0)" ::: "memory");
        __builtin_amdgcn_sched_barrier(0);

        const float* __restrict__ wcp = Wc + a * (2 * HXD * HXD) + og * 8;
        const float* __restrict__ bcp = bc + a * HXD + og * 8;
        float acc[8];
        {
            float4 bv0 = *reinterpret_cast<const float4*>(bcp + 0);
            float4 bv1 = *reinterpret_cast<const float4*>(bcp + 4);
            acc[0] = bv0.x; acc[1] = bv0.y; acc[2] = bv0.z; acc[3] = bv0.w;
            acc[4] = bv1.x; acc[5] = bv1.y; acc[6] = bv1.z; acc[7] = bv1.w;
        }
        const _Float16* hbase = &s_hid[lb * BFST + a * HXD];
        #pragma unroll 8
        for (int k = 0; k < HXD; ++k) {
            const float ci = (float)hbase[k];
            const float* wr = wcp + k * HXD;
            float4 wv0 = *reinterpret_cast<const float4*>(wr + 0);
            float4 wv1 = *reinterpret_cast<const float4*>(wr + 4);
            acc[0] = fmaf(ci, wv0.x, acc[0]);
            acc[1] = fmaf(ci, wv0.y, acc[1]);
            acc[2] = fmaf(ci, wv0.z, acc[2]);
            acc[3] = fmaf(ci, wv0.w, acc[3]);
            acc[4] = fmaf(ci, wv1.x, acc[4]);
            acc[5] = fmaf(ci, wv1.y, acc[5]);
            acc[6] = fmaf(ci, wv1.z, acc[6]);
            acc[7] = fmaf(ci, wv1.w, acc[7]);
        }
        #pragma unroll 8
        for (int k2 = 0; k2 < HXD; ++k2) {
            const float ci = s_h[wave][lb][k2];
            const float* wr = wcp + (HXD + k2) * HXD;
            float4 wv0 = *reinterpret_cast<const float4*>(wr + 0);
            float4 wv1 = *reinterpret_cast<const float4*>(wr + 4);
            acc[0] = fmaf(ci, wv0.x, acc[0]);
            acc[1] = fmaf(ci, wv0.y, acc[1]);
            acc[2] = fmaf(ci, wv0.z, acc[2]);
            acc[3] = fmaf(ci, wv0.w, acc[3]);
            acc[4] = fmaf(ci, wv1.x, acc[4]);
            acc[5] = fmaf(ci, wv1.y, acc[5]);
            acc[6] = fmaf(ci, wv1.z, acc[6]);
            acc[7] = fmaf(ci, wv1.w, acc[7]);
        }
        float qv[NACTD];
        #pragma unroll
        for (int o = 0; o < NACTD; ++o) qv[o] = 0.0f;
        const float* __restrict__ wdp = Wd + a * (HXD * NACTD) + og * 8 * NACTD;
        #pragma unroll
        for (int i = 0; i < 8; ++i) {
            float h2 = tanhf(acc[i]);
            #pragma unroll
            for (int o = 0; o < NACTD; ++o)
                qv[o] = fmaf(h2, wdp[i * NACTD + o], qv[o]);
        }
        #pragma unroll
        for (int o = 0; o < NACTD; ++o) {
            qv[o] += __shfl_xor(qv[o], 8, 64);
            qv[o] += __shfl_xor(qv[o], 16, 64);
            qv[o] += __shfl_xor(qv[o], 32, 64);
        }
        if (og == 0) {
            float* op = out + ((size_t)(b0 + lb) * NAGENTS + a) * NACTD;
            const float* bdp = bd + a * NACTD;
            #pragma unroll
            for (int o = 0; o < NACTD; ++o) op[o] = qv[o] + bdp[o];
        }
    }
}

extern "C" void kernel_launch(void* const* d_in, const int* in_sizes, int n_in,
                              void* d_out, int out_size, void* d_ws, size_t ws_size,
                              hipStream_t stream) {
    (void)out_size;
    if (n_in < 9) return;
    const float* obs = (const float*)d_in[0];
    const float* W1  = (const float*)d_in[1];
    const float* b1v = (const float*)d_in[2];
    const float* W2  = (const float*)d_in[3];
    const float* b2v = (const float*)d_in[4];
    const float* Wc  = (const float*)d_in[5];
    const float* bcv = (const float*)d_in[6];
    const float* Wd  = (const float*)d_in[7];
    const float* bdv = (const float*)d_in[8];
    float* out = (float*)d_out;
    const int Btot = in_sizes[0] / (NAGENTS * NOBSV);  // 16384

    const size_t bufHalves = (size_t)Btot * NAGENTS * HXD;
    const size_t need1 = bufHalves * 2 * 2;                       // hid + cms (f16)
    const size_t fragBytes = (size_t)2 * NAGENTS * 2 * 1024 * 16; // 2 MB frag images
    dim3 blk(256);
    if (ws_size >= need1 + fragBytes && (Btot % 128) == 0) {
        _Float16* hid = (_Float16*)d_ws;
        _Float16* cms = hid + bufHalves;
        h8* wfrag = (h8*)((char*)d_ws + need1);
        k0_prep<<<dim3(NAGENTS), blk, 0, stream>>>(W2, Wc, wfrag);
        k1_encoder<<<dim3(Btot / 128, NAGENTS), blk, 0, stream>>>(
            obs, W1, b1v, W2, b2v, hid, wfrag);
        k2_comms<<<dim3(Btot / 8), blk, 0, stream>>>(obs, hid, cms);
        k3_head<<<dim3(Btot / 128, NAGENTS), blk, 0, stream>>>(
            hid, cms, Wc, bcv, Wd, bdv, out, wfrag);
    } else if (ws_size >= need1 && (Btot % 128) == 0) {
        _Float16* hid = (_Float16*)d_ws;
        _Float16* cms = hid + bufHalves;
        k1_encoder<<<dim3(Btot / 128, NAGENTS), blk, 0, stream>>>(
            obs, W1, b1v, W2, b2v, hid, (const h8*)nullptr);
        k2_comms<<<dim3(Btot / 8), blk, 0, stream>>>(obs, hid, cms);
        k3_head<<<dim3(Btot / 128, NAGENTS), blk, 0, stream>>>(
            hid, cms, Wc, bcv, Wd, bdv, out, (const h8*)nullptr);
    } else {
        qnet_fused_fb<<<dim3(Btot / TBATCH), dim3(256), 0, stream>>>(
            obs, W1, b1v, W2, b2v, Wc, bcv, Wd, bdv, out);
    }
}

// Round 11
// 117.517 us; speedup vs baseline: 172.3409x; 1.2390x over previous
//
#include <hip/hip_runtime.h>

#define NAGENTS 32
#define NOBSV   2
#define H1D     128
#define HXD     64
#define NACTD   5

typedef _Float16 h8 __attribute__((ext_vector_type(8)));
typedef float f32x4 __attribute__((ext_vector_type(4)));

// MFMA 16x16x32 f16 layouts (validated rounds 8-10):
//   A: lane l holds A[l&15][(l>>4)*8 + j]
//   B: lane l holds B[(l>>4)*8 + j][l&15]
//   D: reg r holds D[(l>>4)*4 + r][l&15]
// ci buffer: [row][agent][128] f16 — cols 0..63 = hidden (K1), 64..127 = comms (K2).

// ================= Kernel 0: weight fragment prep (per agent, once) =================
__global__ __launch_bounds__(256, 4) void k0_prep(
    const float* __restrict__ W2, const float* __restrict__ Wc,
    h8* __restrict__ wfrag)
{
    const int a = blockIdx.x;
    const int tid = threadIdx.x;
    #pragma unroll
    for (int mat = 0; mat < 2; ++mat) {
        const float* src = (mat == 0 ? W2 : Wc) + (size_t)a * (H1D * HXD);
        h8* dhi = wfrag + ((size_t)(mat * NAGENTS + a) * 2 + 0) * 1024;
        h8* dlo = wfrag + ((size_t)(mat * NAGENTS + a) * 2 + 1) * 1024;
        #pragma unroll
        for (int s4 = 0; s4 < 4; ++s4) {
            const int s  = tid + s4 * 256;
            const int fi = s >> 6, ln = s & 63;
            const int k0  = (fi >> 2) * 32 + (ln >> 4) * 8;
            const int col = (fi & 3) * 16 + (ln & 15);
            h8 whi, wlo;
            #pragma unroll
            for (int j = 0; j < 8; ++j) {
                float w = src[(size_t)(k0 + j) * HXD + col];
                _Float16 hi = (_Float16)w;
                whi[j] = hi;
                wlo[j] = (_Float16)(w - (float)hi);
            }
            dhi[s] = whi;
            dlo[s] = wlo;
        }
    }
}

// ============================ Kernel 1: encoder ============================
// grid (NAGENTS, B/128). h computed per-lane directly in fragment layout.
__global__ __launch_bounds__(256, 4) void k1_encoder(
    const float* __restrict__ obs, const float* __restrict__ W1,
    const float* __restrict__ b1, const float* __restrict__ W2,
    const float* __restrict__ b2, _Float16* __restrict__ ci,
    const h8* __restrict__ wfrag)
{
    __shared__ h8    s_wf[2][16][64];
    __shared__ float s_w1a[H1D], s_w1b[H1D], s_b1[H1D], s_b2[HXD];
    __shared__ float s_ob[128][2];

    const int a   = blockIdx.x;
    const int r0  = blockIdx.y * 128;
    const int tid = threadIdx.x;
    const int wv  = tid >> 6, lane = tid & 63;
    const int l15 = lane & 15, lq = lane >> 4;

    {
        const float* w1p = W1 + a * (NOBSV * H1D);
        if (tid < H1D) {
            s_w1a[tid] = w1p[tid];
            s_w1b[tid] = w1p[H1D + tid];
            s_b1[tid]  = b1[a * H1D + tid];
        } else if (tid < H1D + HXD) {
            s_b2[tid - H1D] = b2[a * HXD + (tid - H1D)];
        }
        if (tid < 128) {
            const float2 ov = *reinterpret_cast<const float2*>(
                obs + ((size_t)(r0 + tid) * NAGENTS + a) * NOBSV);
            s_ob[tid][0] = ov.x; s_ob[tid][1] = ov.y;
        }
        if (wfrag) {
            const h8* srcf = wfrag + (size_t)a * 2048;
            h8* dstf = &s_wf[0][0][0];
            #pragma unroll
            for (int c = 0; c < 8; ++c) dstf[tid + c * 256] = srcf[tid + c * 256];
        } else {
            const float* wsrc = W2 + (size_t)a * (H1D * HXD);
            #pragma unroll
            for (int s4 = 0; s4 < 4; ++s4) {
                const int s  = tid + s4 * 256;
                const int fi = s >> 6, ln = s & 63;
                const int k0  = (fi >> 2) * 32 + (ln >> 4) * 8;
                const int col = (fi & 3) * 16 + (ln & 15);
                h8 whi, wlo;
                #pragma unroll
                for (int j = 0; j < 8; ++j) {
                    float w = wsrc[(size_t)(k0 + j) * HXD + col];
                    _Float16 hi = (_Float16)w;
                    whi[j] = hi;
                    wlo[j] = (_Float16)(w - (float)hi);
                }
                s_wf[0][fi][ln] = whi;
                s_wf[1][fi][ln] = wlo;
            }
        }
    }
    __syncthreads();

    const float o0r0 = s_ob[wv * 32 + l15][0],      o1r0 = s_ob[wv * 32 + l15][1];
    const float o0r1 = s_ob[wv * 32 + 16 + l15][0], o1r1 = s_ob[wv * 32 + 16 + l15][1];

    f32x4 acc[2][4];
    #pragma unroll
    for (int m = 0; m < 2; ++m)
        #pragma unroll
        for (int n = 0; n < 4; ++n) {
            const float bv = s_b2[n * 16 + l15];
            acc[m][n] = (f32x4){bv, bv, bv, bv};
        }
    #pragma unroll
    for (int kt = 0; kt < 4; ++kt) {
        h8 af0, af1;
        #pragma unroll
        for (int j = 0; j < 8; ++j) {
            const int k = kt * 32 + lq * 8 + j;
            const float wa = s_w1a[k], wb = s_w1b[k], bb = s_b1[k];
            af0[j] = (_Float16)fmaxf(fmaf(o1r0, wb, fmaf(o0r0, wa, bb)), 0.0f);
            af1[j] = (_Float16)fmaxf(fmaf(o1r1, wb, fmaf(o0r1, wa, bb)), 0.0f);
        }
        #pragma unroll
        for (int n = 0; n < 4; ++n) {
            h8 bh = s_wf[0][kt * 4 + n][lane];
            h8 bl = s_wf[1][kt * 4 + n][lane];
            acc[0][n] = __builtin_amdgcn_mfma_f32_16x16x32_f16(af0, bh, acc[0][n], 0, 0, 0);
            acc[1][n] = __builtin_amdgcn_mfma_f32_16x16x32_f16(af1, bh, acc[1][n], 0, 0, 0);
            acc[0][n] = __builtin_amdgcn_mfma_f32_16x16x32_f16(af0, bl, acc[0][n], 0, 0, 0);
            acc[1][n] = __builtin_amdgcn_mfma_f32_16x16x32_f16(af1, bl, acc[1][n], 0, 0, 0);
        }
    }
    #pragma unroll
    for (int m = 0; m < 2; ++m)
        #pragma unroll
        for (int r = 0; r < 4; ++r) {
            const int row = wv * 32 + m * 16 + lq * 4 + r;
            _Float16* dst = ci + ((size_t)(r0 + row) * NAGENTS + a) * 128;
            #pragma unroll
            for (int n = 0; n < 4; ++n)
                dst[n * 16 + l15] = (_Float16)fmaxf(acc[m][n][r], 0.0f);
        }
}

// ========================= Kernel 2: mask + comms (MFMA) =========================
// grid (B/8). Wave w owns rows 2w,2w+1; writes comms to ci cols 64..127.
__global__ __launch_bounds__(256, 2) void k2_comms(
    const float* __restrict__ obs, _Float16* __restrict__ ci)
{
    __shared__ __align__(16) _Float16 s_tt[8][64][40];
    __shared__ __align__(16) _Float16 s_m[8][32][40];
    __shared__ float s_o[8][66];
    __shared__ float s_J[8][32];

    const int r0  = blockIdx.x * 8;
    const int tid = threadIdx.x;
    const int wv  = tid >> 6, lane = tid & 63;
    const int l15 = lane & 15, lq = lane >> 4;

    if (tid < 128) {
        const float4 v = reinterpret_cast<const float4*>(obs + (size_t)r0 * NAGENTS * NOBSV)[tid];
        const int row = tid >> 4, seg = tid & 15;
        *reinterpret_cast<float4*>(&s_o[row][seg * 4]) = v;
    }
    __syncthreads();

    const int row = tid >> 5;
    const int u   = tid & 31;

    {   // transposed hidden (ci cols 0..63)
        const h8* src = reinterpret_cast<const h8*>(
            ci + ((size_t)(r0 + row) * NAGENTS + u) * 128);
        #pragma unroll
        for (int c = 0; c < 8; ++c) {
            h8 v = src[c];
            #pragma unroll
            for (int e = 0; e < 8; ++e) s_tt[row][c * 8 + e][u] = v[e];
        }
    }
    {   // mask row (f64, bit-matches numpy-f64)
        unsigned int bits = 0u;
        const double xi = (double)s_o[row][u * 2 + 0] * 2.0;
        const double yi = (double)s_o[row][u * 2 + 1] * 6.0;
        #pragma unroll
        for (int j = 0; j < NAGENTS; ++j) {
            double xj = (double)s_o[row][j * 2 + 0] * 2.0;
            double yj = (double)s_o[row][j * 2 + 1] * 6.0;
            double d = fabs(xi - xj) + fabs(yi - yj);
            if (d > 0.0 && d < 2.0) bits |= (1u << j);
        }
        s_J[row][u] = fmaxf((float)__popc(bits), 1.0f);
        #pragma unroll
        for (int c = 0; c < 4; ++c) {
            h8 mv;
            #pragma unroll
            for (int e = 0; e < 8; ++e)
                mv[e] = ((bits >> (c * 8 + e)) & 1u) ? (_Float16)1.0f : (_Float16)0.0f;
            *reinterpret_cast<h8*>(&s_m[row][u][c * 8]) = mv;
        }
    }
    asm volatile("s_waitcnt lgkmcnt(0)" ::: "memory");
    __builtin_amdgcn_sched_barrier(0);

    #pragma unroll
    for (int rr = 0; rr < 2; ++rr) {
        const int rw = wv * 2 + rr;
        h8 a0 = *reinterpret_cast<const h8*>(&s_m[rw][l15][lq * 8]);
        h8 a1 = *reinterpret_cast<const h8*>(&s_m[rw][16 + l15][lq * 8]);
        f32x4 acc[2][4];
        #pragma unroll
        for (int m = 0; m < 2; ++m)
            #pragma unroll
            for (int n = 0; n < 4; ++n) acc[m][n] = (f32x4){0.f, 0.f, 0.f, 0.f};
        #pragma unroll
        for (int n = 0; n < 4; ++n) {
            h8 b = *reinterpret_cast<const h8*>(&s_tt[rw][n * 16 + l15][lq * 8]);
            acc[0][n] = __builtin_amdgcn_mfma_f32_16x16x32_f16(a0, b, acc[0][n], 0, 0, 0);
            acc[1][n] = __builtin_amdgcn_mfma_f32_16x16x32_f16(a1, b, acc[1][n], 0, 0, 0);
        }
        #pragma unroll
        for (int m = 0; m < 2; ++m)
            #pragma unroll
            for (int r = 0; r < 4; ++r) {
                const int ai = m * 16 + lq * 4 + r;
                const float Jv = s_J[rw][ai];
                _Float16* dst = ci + ((size_t)(r0 + rw) * NAGENTS + ai) * 128 + 64;
                #pragma unroll
                for (int n = 0; n < 4; ++n)
                    dst[n * 16 + l15] = (_Float16)(acc[m][n][r] / Jv);
            }
    }
}

// ==================== Kernel 3: comm MLP + decoder (MFMA) ====================
// grid (NAGENTS, B/128). A-frags read directly from ci (no LDS staging).
__global__ __launch_bounds__(256, 4) void k3_head(
    const _Float16* __restrict__ ci,
    const float* __restrict__ Wc, const float* __restrict__ bc,
    const float* __restrict__ Wd, const float* __restrict__ bd,
    float* __restrict__ out, const h8* __restrict__ wfrag)
{
    __shared__ h8    s_wf[2][16][64];
    __shared__ float s_wd[HXD][8];
    __shared__ float s_bc[HXD];
    __shared__ float s_bd[8];

    const int a   = blockIdx.x;
    const int r0  = blockIdx.y * 128;
    const int tid = threadIdx.x;
    const int wv  = tid >> 6, lane = tid & 63;
    const int l15 = lane & 15, lq = lane >> 4;

    {
        if (wfrag) {
            const h8* srcf = wfrag + (size_t)(NAGENTS + a) * 2048;
            h8* dstf = &s_wf[0][0][0];
            #pragma unroll
            for (int c = 0; c < 8; ++c) dstf[tid + c * 256] = srcf[tid + c * 256];
        } else {
            const float* wsrc = Wc + (size_t)a * (2 * HXD * HXD);
            #pragma unroll
            for (int s4 = 0; s4 < 4; ++s4) {
                const int s  = tid + s4 * 256;
                const int fi = s >> 6, ln = s & 63;
                const int k0  = (fi >> 2) * 32 + (ln >> 4) * 8;
                const int col = (fi & 3) * 16 + (ln & 15);
                h8 whi, wlo;
                #pragma unroll
                for (int j = 0; j < 8; ++j) {
                    float w = wsrc[(size_t)(k0 + j) * HXD + col];
                    _Float16 hi = (_Float16)w;
                    whi[j] = hi;
                    wlo[j] = (_Float16)(w - (float)hi);
                }
                s_wf[0][fi][ln] = whi;
                s_wf[1][fi][ln] = wlo;
            }
        }
        if (tid < HXD) {
            s_bc[tid] = bc[a * HXD + tid];
            #pragma unroll
            for (int o = 0; o < NACTD; ++o)
                s_wd[tid][o] = Wd[(size_t)a * (HXD * NACTD) + tid * NACTD + o];
        } else if (tid < HXD + NACTD) {
            s_bd[tid - HXD] = bd[a * NACTD + (tid - HXD)];
        }
    }
    __syncthreads();

    const _Float16* rb0 = ci + ((size_t)(r0 + wv * 32 + l15) * NAGENTS + a) * 128;
    const _Float16* rb1 = rb0 + (size_t)16 * NAGENTS * 128;

    f32x4 acc[2][4];
    #pragma unroll
    for (int m = 0; m < 2; ++m)
        #pragma unroll
        for (int n = 0; n < 4; ++n) {
            const float bv = s_bc[n * 16 + l15];
            acc[m][n] = (f32x4){bv, bv, bv, bv};
        }
    #pragma unroll
    for (int kt = 0; kt < 4; ++kt) {
        h8 af0 = *reinterpret_cast<const h8*>(rb0 + kt * 32 + lq * 8);
        h8 af1 = *reinterpret_cast<const h8*>(rb1 + kt * 32 + lq * 8);
        #pragma unroll
        for (int n = 0; n < 4; ++n) {
            h8 bh = s_wf[0][kt * 4 + n][lane];
            h8 bl = s_wf[1][kt * 4 + n][lane];
            acc[0][n] = __builtin_amdgcn_mfma_f32_16x16x32_f16(af0, bh, acc[0][n], 0, 0, 0);
            acc[1][n] = __builtin_amdgcn_mfma_f32_16x16x32_f16(af1, bh, acc[1][n], 0, 0, 0);
            acc[0][n] = __builtin_amdgcn_mfma_f32_16x16x32_f16(af0, bl, acc[0][n], 0, 0, 0);
            acc[1][n] = __builtin_amdgcn_mfma_f32_16x16x32_f16(af1, bl, acc[1][n], 0, 0, 0);
        }
    }

    #pragma unroll
    for (int m = 0; m < 2; ++m)
        #pragma unroll
        for (int r = 0; r < 4; ++r) {
            float qv[NACTD];
            #pragma unroll
            for (int o = 0; o < NACTD; ++o) qv[o] = 0.0f;
            #pragma unroll
            for (int n = 0; n < 4; ++n) {
                const float t = tanhf(acc[m][n][r]);
                const float* wd = s_wd[n * 16 + l15];
                #pragma unroll
                for (int o = 0; o < NACTD; ++o) qv[o] = fmaf(t, wd[o], qv[o]);
            }
            #pragma unroll
            for (int o = 0; o < NACTD; ++o) {
                qv[o] += __shfl_xor(qv[o], 1, 64);
                qv[o] += __shfl_xor(qv[o], 2, 64);
                qv[o] += __shfl_xor(qv[o], 4, 64);
                qv[o] += __shfl_xor(qv[o], 8, 64);
            }
            if (l15 == 0) {
                const int row = wv * 32 + m * 16 + lq * 4 + r;
                float* op = out + ((size_t)(r0 + row) * NAGENTS + a) * NACTD;
                #pragma unroll
                for (int o = 0; o < NACTD; ++o) op[o] = qv[o] + s_bd[o];
            }
        }
}

// ================= Fallback: round-6 fused kernel (passed @991us) =================
#define TBATCH  8
#define NWAVES  4
#define BFST    2056
#define HROWST  132
__global__ __launch_bounds__(256, 3) void qnet_fused_fb(
    const float* __restrict__ obs,
    const float* __restrict__ W1, const float* __restrict__ b1,
    const float* __restrict__ W2, const float* __restrict__ b2,
    const float* __restrict__ Wc, const float* __restrict__ bc,
    const float* __restrict__ Wd, const float* __restrict__ bd,
    float* __restrict__ out)
{
    __shared__ float    s_obs[TBATCH][NAGENTS * 2 + 2];
    __shared__ _Float16 s_hid[TBATCH * BFST];
    __shared__ float    s_h[NWAVES][TBATCH][HROWST];

    const int tid  = threadIdx.x;
    const int wave = tid >> 6;
    const int lane = tid & 63;
    const int lb   = lane & 7;
    const int og   = lane >> 3;
    const int b0   = blockIdx.x * TBATCH;

    {
        const float2* src = reinterpret_cast<const float2*>(obs + (size_t)b0 * (NAGENTS * NOBSV));
        float2 v = src[tid];
        s_obs[tid >> 5][(tid & 31) * 2 + 0] = v.x;
        s_obs[tid >> 5][(tid & 31) * 2 + 1] = v.y;
    }
    __syncthreads();

    const int p_a = tid >> 3;
    const int p_b = tid & 7;
    unsigned int bits = 0u;
    float Jf;
    {
        const double xi = (double)s_obs[p_b][p_a * 2 + 0] * 2.0;
        const double yi = (double)s_obs[p_b][p_a * 2 + 1] * 6.0;
        #pragma unroll
        for (int j = 0; j < NAGENTS; ++j) {
            double xj = (double)s_obs[p_b][j * 2 + 0] * 2.0;
            double yj = (double)s_obs[p_b][j * 2 + 1] * 6.0;
            double d = fabs(xi - xj) + fabs(yi - yj);
            if (d > 0.0 && d < 2.0) bits |= (1u << j);
        }
        Jf = fmaxf((float)__popc(bits), 1.0f);
    }

    #pragma unroll 1
    for (int ai = 0; ai < 8; ++ai) {
        const int a = wave * 8 + ai;
        const float o0 = s_obs[lb][a * 2 + 0];
        const float o1 = s_obs[lb][a * 2 + 1];
        {
            const float* __restrict__ w1a = W1 + a * (NOBSV * H1D) + og * 16;
            const float* __restrict__ w1b = w1a + H1D;
            const float* __restrict__ b1p = b1 + a * H1D + og * 16;
            float* hdst = &s_h[wave][lb][og * 16];
            #pragma unroll
            for (int c = 0; c < 4; ++c) {
                float4 wa = *reinterpret_cast<const float4*>(w1a + 4 * c);
                float4 wb = *reinterpret_cast<const float4*>(w1b + 4 * c);
                float4 bv = *reinterpret_cast<const float4*>(b1p + 4 * c);
                float4 hv;
                hv.x = fmaxf(fmaf(o1, wb.x, fmaf(o0, wa.x, bv.x)), 0.0f);
                hv.y = fmaxf(fmaf(o1, wb.y, fmaf(o0, wa.y, bv.y)), 0.0f);
                hv.z = fmaxf(fmaf(o1, wb.z, fmaf(o0, wa.z, bv.z)), 0.0f);
                hv.w = fmaxf(fmaf(o1, wb.w, fmaf(o0, wa.w, bv.w)), 0.0f);
                *reinterpret_cast<float4*>(hdst + 4 * c) = hv;
            }
        }
        asm volatile("s_waitcnt lgkmcnt(0)" ::: "memory");
        __builtin_amdgcn_sched_barrier(0);

        const float* __restrict__ w2p = W2 + a * (H1D * HXD) + og * 8;
        const float* __restrict__ b2p = b2 + a * HXD + og * 8;
        float acc[8];
        {
            float4 bv0 = *reinterpret_cast<const float4*>(b2p + 0);
            float4 bv1 = *reinterpret_cast<const float4*>(b2p + 4);
            acc[0] = bv0.x; acc[1] = bv0.y; acc[2] = bv0.z; acc[3] = bv0.w;
            acc[4] = bv1.x; acc[5] = bv1.y; acc[6] = bv1.z; acc[7] = bv1.w;
        }
        const float* hsrc = &s_h[wave][lb][0];
        #pragma unroll 8
        for (int k = 0; k < H1D; ++k) {
            const float hv = hsrc[k];
            const float* wr = w2p + k * HXD;
            float4 wv0 = *reinterpret_cast<const float4*>(wr + 0);
            float4 wv1 = *reinterpret_cast<const float4*>(wr + 4);
            acc[0] = fmaf(hv, wv0.x, acc[0]);
            acc[1] = fmaf(hv, wv0.y, acc[1]);
            acc[2] = fmaf(hv, wv0.z, acc[2]);
            acc[3] = fmaf(hv, wv0.w, acc[3]);
            acc[4] = fmaf(hv, wv1.x, acc[4]);
            acc[5] = fmaf(hv, wv1.y, acc[5]);
            acc[6] = fmaf(hv, wv1.z, acc[6]);
            acc[7] = fmaf(hv, wv1.w, acc[7]);
        }
        h8 hh;
        #pragma unroll
        for (int i = 0; i < 8; ++i) hh[i] = (_Float16)fmaxf(acc[i], 0.0f);
        *reinterpret_cast<h8*>(&s_hid[lb * BFST + a * HXD + og * 8]) = hh;
    }
    __syncthreads();

    #pragma unroll 1
    for (int ai = 0; ai < 8; ++ai) {
        const int a = wave * 8 + ai;
        const int srcm = ai * 8 + lb;
        const unsigned int mbits = (unsigned int)__shfl((int)bits, srcm, 64);
        const float Jv = __shfl(Jf, srcm, 64);

        float cm8[8];
        #pragma unroll
        for (int i = 0; i < 8; ++i) cm8[i] = 0.0f;
        {
            const _Float16* hrow = &s_hid[lb * BFST + og * 8];
            #pragma unroll 8
            for (int j = 0; j < NAGENTS; ++j) {
                const float m = (float)((mbits >> j) & 1u);
                h8 v = *reinterpret_cast<const h8*>(hrow + j * HXD);
                cm8[0] = fmaf(m, (float)v[0], cm8[0]);
                cm8[1] = fmaf(m, (float)v[1], cm8[1]);
                cm8[2] = fmaf(m, (float)v[2], cm8[2]);
                cm8[3] = fmaf(m, (float)v[3], cm8[3]);
                cm8[4] = fmaf(m, (float)v[4], cm8[4]);
                cm8[5] = fmaf(m, (float)v[5], cm8[5]);
                cm8[6] = fmaf(m, (float)v[6], cm8[6]);
                cm8[7] = fmaf(m, (float)v[7], cm8[7]);
            }
        }
        {
            float* cw = &s_h[wave][lb][og * 8];
            *reinterpret_cast<float4*>(cw + 0) =
                make_float4(cm8[0]/Jv, cm8[1]/Jv, cm8[2]/Jv, cm8[3]/Jv);
            *reinterpret_cast<float4*>(cw + 4) =
                make_float4(cm8[4]/Jv, cm8[5]/Jv, cm8[6]/Jv, cm8[7]/Jv);
        }
        asm volatile("s_waitcnt lgkmcnt(0)" ::: "memory");
        __builtin_amdgcn_sched_barrier(0);

        const float* __restrict__ wcp = Wc + a * (2 * HXD * HXD) + og * 8;
        const float* __restrict__ bcp = bc + a * HXD + og * 8;
        float acc[8];
        {
            float4 bv0 = *reinterpret_cast<const float4*>(bcp + 0);
            float4 bv1 = *reinterpret_cast<const float4*>(bcp + 4);
            acc[0] = bv0.x; acc[1] = bv0.y; acc[2] = bv0.z; acc[3] = bv0.w;
            acc[4] = bv1.x; acc[5] = bv1.y; acc[6] = bv1.z; acc[7] = bv1.w;
        }
        const _Float16* hbase = &s_hid[lb * BFST + a * HXD];
        #pragma unroll 8
        for (int k = 0; k < HXD; ++k) {
            const float ci2 = (float)hbase[k];
            const float* wr = wcp + k * HXD;
            float4 wv0 = *reinterpret_cast<const float4*>(wr + 0);
            float4 wv1 = *reinterpret_cast<const float4*>(wr + 4);
            acc[0] = fmaf(ci2, wv0.x, acc[0]);
            acc[1] = fmaf(ci2, wv0.y, acc[1]);
            acc[2] = fmaf(ci2, wv0.z, acc[2]);
            acc[3] = fmaf(ci2, wv0.w, acc[3]);
            acc[4] = fmaf(ci2, wv1.x, acc[4]);
            acc[5] = fmaf(ci2, wv1.y, acc[5]);
            acc[6] = fmaf(ci2, wv1.z, acc[6]);
            acc[7] = fmaf(ci2, wv1.w, acc[7]);
        }
        #pragma unroll 8
        for (int k2 = 0; k2 < HXD; ++k2) {
            const float ci2 = s_h[wave][lb][k2];
            const float* wr = wcp + (HXD + k2) * HXD;
            float4 wv0 = *reinterpret_cast<const float4*>(wr + 0);
            float4 wv1 = *reinterpret_cast<const float4*>(wr + 4);
            acc[0] = fmaf(ci2, wv0.x, acc[0]);
            acc[1] = fmaf(ci2, wv0.y, acc[1]);
            acc[2] = fmaf(ci2, wv0.z, acc[2]);
            acc[3] = fmaf(ci2, wv0.w, acc[3]);
            acc[4] = fmaf(ci2, wv1.x, acc[4]);
            acc[5] = fmaf(ci2, wv1.y, acc[5]);
            acc[6] = fmaf(ci2, wv1.z, acc[6]);
            acc[7] = fmaf(ci2, wv1.w, acc[7]);
        }
        float qv[NACTD];
        #pragma unroll
        for (int o = 0; o < NACTD; ++o) qv[o] = 0.0f;
        const float* __restrict__ wdp = Wd + a * (HXD * NACTD) + og * 8 * NACTD;
        #pragma unroll
        for (int i = 0; i < 8; ++i) {
            float h2 = tanhf(acc[i]);
            #pragma unroll
            for (int o = 0; o < NACTD; ++o)
                qv[o] = fmaf(h2, wdp[i * NACTD + o], qv[o]);
        }
        #pragma unroll
        for (int o = 0; o < NACTD; ++o) {
            qv[o] += __shfl_xor(qv[o], 8, 64);
            qv[o] += __shfl_xor(qv[o], 16, 64);
            qv[o] += __shfl_xor(qv[o], 32, 64);
        }
        if (og == 0) {
            float* op = out + ((size_t)(b0 + lb) * NAGENTS + a) * NACTD;
            const float* bdp = bd + a * NACTD;
            #pragma unroll
            for (int o = 0; o < NACTD; ++o) op[o] = qv[o] + bdp[o];
        }
    }
}

extern "C" void kernel_launch(void* const* d_in, const int* in_sizes, int n_in,
                              void* d_out, int out_size, void* d_ws, size_t ws_size,
                              hipStream_t stream) {
    (void)out_size;
    if (n_in < 9) return;
    const float* obs = (const float*)d_in[0];
    const float* W1  = (const float*)d_in[1];
    const float* b1v = (const float*)d_in[2];
    const float* W2  = (const float*)d_in[3];
    const float* b2v = (const float*)d_in[4];
    const float* Wc  = (const float*)d_in[5];
    const float* bcv = (const float*)d_in[6];
    const float* Wd  = (const float*)d_in[7];
    const float* bdv = (const float*)d_in[8];
    float* out = (float*)d_out;
    const int Btot = in_sizes[0] / (NAGENTS * NOBSV);  // 16384

    const size_t ciBytes   = (size_t)Btot * NAGENTS * 128 * 2;    // 134 MB
    const size_t fragBytes = (size_t)2 * NAGENTS * 2 * 1024 * 16; // 2 MB
    dim3 blk(256);
    if (ws_size >= ciBytes + fragBytes && (Btot % 128) == 0) {
        _Float16* ci = (_Float16*)d_ws;
        h8* wfrag = (h8*)((char*)d_ws + ciBytes);
        k0_prep<<<dim3(NAGENTS), blk, 0, stream>>>(W2, Wc, wfrag);
        k1_encoder<<<dim3(NAGENTS, Btot / 128), blk, 0, stream>>>(
            obs, W1, b1v, W2, b2v, ci, wfrag);
        k2_comms<<<dim3(Btot / 8), blk, 0, stream>>>(obs, ci);
        k3_head<<<dim3(NAGENTS, Btot / 128), blk, 0, stream>>>(
            ci, Wc, bcv, Wd, bdv, out, wfrag);
    } else if (ws_size >= ciBytes && (Btot % 128) == 0) {
        _Float16* ci = (_Float16*)d_ws;
        k1_encoder<<<dim3(NAGENTS, Btot / 128), blk, 0, stream>>>(
            obs, W1, b1v, W2, b2v, ci, (const h8*)nullptr);
        k2_comms<<<dim3(Btot / 8), blk, 0, stream>>>(obs, ci);
        k3_head<<<dim3(NAGENTS, Btot / 128), blk, 0, stream>>>(
            ci, Wc, bcv, Wd, bdv, out, (const h8*)nullptr);
    } else {
        qnet_fused_fb<<<dim3(Btot / TBATCH), dim3(256), 0, stream>>>(
            obs, W1, b1v, W2, b2v, Wc, bcv, Wd, bdv, out);
    }
}